// Round 11
// baseline (253.703 us; speedup 1.0000x reference)
//
#include <hip/hip_runtime.h>
#include <hip/hip_bf16.h>
#include <math.h>

// Problem constants (from reference): D = ATTN = 128, N_NODE = 100000.
#define DIM 128
#define N_NODE_C 100000

typedef __attribute__((ext_vector_type(8))) short  bf16x8;
typedef __attribute__((ext_vector_type(4))) float  f32x4;

__device__ inline unsigned short f2bf_rne(float f) {
    unsigned u = __float_as_uint(f);
    return (unsigned short)((u + 0x7FFFu + ((u >> 16) & 1u)) >> 16);
}
__device__ inline float bf2f(unsigned short u) {
    return __uint_as_float(((unsigned)u) << 16);
}

// ---------------------------------------------------------------------------
// Fused setup kernel (128 threads/block):
//   blocks [0, B)            : qrW[b]   = rela[q_rel[b]] @ Wqr_w + Wqr_b
//   blocks [B, B+RV)         : relhr[r] = [ rela[r] @ Wr | rela[r] ]  (256 c)
//   blocks [B+RV, B+RV+32)   : pack Ws / Wh into MFMA B-fragment layout
//   blocks [B+RV+32, ...)    : zero deg[] (replaces hipMemsetAsync)
// ---------------------------------------------------------------------------
__global__ __launch_bounds__(128) void setup_kernel(
    const int* __restrict__ q_rel,
    const float* __restrict__ rela,
    const float* __restrict__ Wqr_w,
    const float* __restrict__ Wqr_b,
    const float* __restrict__ Wr,
    const float* __restrict__ Ws,
    const float* __restrict__ Wh,
    float* __restrict__ qrW,
    float* __restrict__ relhr,
    uint4* __restrict__ wpack_s,
    uint4* __restrict__ wpack_h,
    int* deg, int N,
    int B, int RV)
{
    const int blk = blockIdx.x;
    const int j   = threadIdx.x;

    if (blk < B + RV) {
        __shared__ float emb[DIM];
        const float* W;
        float* out;
        float bias = 0.f;
        int row;
        if (blk < B) {
            row  = q_rel[blk];
            W    = Wqr_w;
            out  = qrW + (size_t)blk * DIM;
            bias = Wqr_b[j];
        } else {
            row = blk - B;
            W   = Wr;
            out = relhr + (size_t)(blk - B) * 256;
        }
        emb[j] = rela[(size_t)row * DIM + j];
        __syncthreads();

        float acc = bias;
#pragma unroll 8
        for (int k = 0; k < DIM; ++k)
            acc += emb[k] * W[k * DIM + j];
        out[j] = acc;
        if (blk >= B)
            out[128 + j] = emb[j];      // rela copy: free (already in LDS)
        return;
    }

    if (blk < B + RV + 32) {
        // --- pack path ---
        const int pid = blk - (B + RV);          // 0..31
        const float* W = (pid < 16) ? Ws : Wh;
        uint4* dst     = (pid < 16) ? wpack_s : wpack_h;
        const int id   = (pid & 15) * 128 + j;   // 0..2047
        const int ct   = id >> 8;
        const int kb   = (id >> 6) & 3;
        const int lane = id & 63;
        const int col  = ct * 16 + (lane & 15);
        const int k0   = kb * 32 + (lane >> 4) * 8;

        unsigned v[4];
#pragma unroll
        for (int p = 0; p < 4; ++p) {
            unsigned lo = f2bf_rne(W[(size_t)(k0 + 2 * p)     * DIM + col]);
            unsigned hi = f2bf_rne(W[(size_t)(k0 + 2 * p + 1) * DIM + col]);
            v[p] = lo | (hi << 16);
        }
        dst[id] = make_uint4(v[0], v[1], v[2], v[3]);
        return;
    }

    // --- deg zeroing path ---
    if (deg) {
        int i = (blk - (B + RV + 32)) * 128 + j;
        if (i < N) deg[i] = 0;
    }
}

// ---------------------------------------------------------------------------
// Fused GEMM + histogram. Heterogeneous grid:
//   blocks [0, Nb)      : hsub[M x 256] bf16 = [ bf16(A) | A @ W ]
//   blocks [Nb, Nb+Hb)  : deg histogram of edges obj column.
// C/D layout (HW-verified): col = lane&15, row = (lane>>4)*4 + reg.
// ---------------------------------------------------------------------------
__global__ __launch_bounds__(256) void gemm_hist_kernel(
    const float* __restrict__ A, const uint4* __restrict__ Wpack,
    unsigned short* __restrict__ H, int M,
    const int* __restrict__ edges, int* __restrict__ deg, int E, int Nb)
{
    if ((int)blockIdx.x >= Nb) {
        int i = ((int)blockIdx.x - Nb) * 256 + threadIdx.x;
        if (i < E) atomicAdd(&deg[edges[(size_t)i * 6 + 5]], 1);
        return;
    }

    __shared__ uint4 wlds[2048];   // [ct][kb][lane], 32 KB
    const int t = threadIdx.x;
#pragma unroll
    for (int p = 0; p < 8; ++p)
        wlds[p * 256 + t] = Wpack[p * 256 + t];
    __syncthreads();

    const int wave = t >> 6;
    const int lane = t & 63;
    const int r    = lane & 15;
    const int g    = lane >> 4;
    const int row0 = blockIdx.x * 64 + wave * 16;

    int arow = row0 + r;
    if (arow >= M) arow = M - 1;
    const float* Ap = A + (size_t)arow * DIM + g * 8;

    bf16x8 afrag[4];
#pragma unroll
    for (int kb = 0; kb < 4; ++kb) {
        const float4 lo = *(const float4*)(Ap + kb * 32);
        const float4 hi = *(const float4*)(Ap + kb * 32 + 4);
        bf16x8 a;
        a[0] = (short)f2bf_rne(lo.x); a[1] = (short)f2bf_rne(lo.y);
        a[2] = (short)f2bf_rne(lo.z); a[3] = (short)f2bf_rne(lo.w);
        a[4] = (short)f2bf_rne(hi.x); a[5] = (short)f2bf_rne(hi.y);
        a[6] = (short)f2bf_rne(hi.z); a[7] = (short)f2bf_rne(hi.w);
        afrag[kb] = a;
    }

    // bf16(A) into cols 0..127 (free conversion).
#pragma unroll
    for (int kb = 0; kb < 4; ++kb)
        *(bf16x8*)&H[(size_t)arow * 256 + kb * 32 + g * 8] = afrag[kb];

#pragma unroll
    for (int ct = 0; ct < 8; ++ct) {
        f32x4 acc = {0.f, 0.f, 0.f, 0.f};
#pragma unroll
        for (int kb = 0; kb < 4; ++kb) {
            bf16x8 b = *(bf16x8*)&wlds[ct * 256 + kb * 64 + lane];
            acc = __builtin_amdgcn_mfma_f32_16x16x32_bf16(afrag[kb], b, acc, 0, 0, 0);
        }
        const int col = ct * 16 + r;
#pragma unroll
        for (int jj = 0; jj < 4; ++jj) {
            const int row = row0 + g * 4 + jj;
            if (row < M)
                H[(size_t)row * 256 + 128 + col] = f2bf_rne(acc[jj]);
        }
    }
}

// ---------------------------------------------------------------------------
// Final GEMM: C[M x 128] f32 = A @ Wh.
// ABF16 = 1: A is bf16 [M x 128] in workspace (direct fragment loads).
// ABF16 = 0: A is f32 in d_out; in-place safe (wave reads its own 16 rows
//            through registers before storing them).
// ---------------------------------------------------------------------------
template <int ABF16>
__global__ __launch_bounds__(256) void gemm_final(
    const void* Av, const uint4* __restrict__ Wpack, float* C, int M)
{
    __shared__ uint4 wlds[2048];
    const int t = threadIdx.x;
#pragma unroll
    for (int p = 0; p < 8; ++p)
        wlds[p * 256 + t] = Wpack[p * 256 + t];
    __syncthreads();

    const int wave = t >> 6;
    const int lane = t & 63;
    const int r    = lane & 15;
    const int g    = lane >> 4;
    const int row0 = blockIdx.x * 64 + wave * 16;

    int arow = row0 + r;
    if (arow >= M) arow = M - 1;

    bf16x8 afrag[4];
    if (ABF16) {
        const unsigned short* Ab = (const unsigned short*)Av + (size_t)arow * DIM + g * 8;
#pragma unroll
        for (int kb = 0; kb < 4; ++kb)
            afrag[kb] = *(const bf16x8*)(Ab + kb * 32);
    } else {
        const float* Ap = (const float*)Av + (size_t)arow * DIM + g * 8;
#pragma unroll
        for (int kb = 0; kb < 4; ++kb) {
            const float4 lo = *(const float4*)(Ap + kb * 32);
            const float4 hi = *(const float4*)(Ap + kb * 32 + 4);
            bf16x8 a;
            a[0] = (short)f2bf_rne(lo.x); a[1] = (short)f2bf_rne(lo.y);
            a[2] = (short)f2bf_rne(lo.z); a[3] = (short)f2bf_rne(lo.w);
            a[4] = (short)f2bf_rne(hi.x); a[5] = (short)f2bf_rne(hi.y);
            a[6] = (short)f2bf_rne(hi.z); a[7] = (short)f2bf_rne(hi.w);
            afrag[kb] = a;
        }
    }

#pragma unroll
    for (int ct = 0; ct < 8; ++ct) {
        f32x4 acc = {0.f, 0.f, 0.f, 0.f};
#pragma unroll
        for (int kb = 0; kb < 4; ++kb) {
            bf16x8 b = *(bf16x8*)&wlds[ct * 256 + kb * 64 + lane];
            acc = __builtin_amdgcn_mfma_f32_16x16x32_bf16(afrag[kb], b, acc, 0, 0, 0);
        }
        const int col = ct * 16 + r;
#pragma unroll
        for (int jj = 0; jj < 4; ++jj) {
            const int row = row0 + g * 4 + jj;
            if (row < M)
                C[(size_t)row * DIM + col] = acc[jj];
        }
    }
}

// ---------------------------------------------------------------------------
// Sort scaffolding.
// ---------------------------------------------------------------------------
__global__ __launch_bounds__(256) void scan1_kernel(
    const int* __restrict__ in, int* __restrict__ out,
    int* __restrict__ bsum, int n)
{
    __shared__ int ts[256];
    const int tid  = threadIdx.x;
    const int base = blockIdx.x * 2048 + tid * 8;

    int v[8];
    int run = 0;
#pragma unroll
    for (int i = 0; i < 8; ++i) {
        int x = (base + i < n) ? in[base + i] : 0;
        v[i] = run;
        run += x;
    }
    ts[tid] = run;
    __syncthreads();
    for (int off = 1; off < 256; off <<= 1) {
        int x = (tid >= off) ? ts[tid - off] : 0;
        __syncthreads();
        ts[tid] += x;
        __syncthreads();
    }
    const int excl = ts[tid] - run;
#pragma unroll
    for (int i = 0; i < 8; ++i)
        if (base + i < n) out[base + i] = v[i] + excl;
    if (tid == 255) bsum[blockIdx.x] = ts[255];
}

// Adds cross-block prefix (bsum holds block totals), duplicates into cursor,
// and emits sampled_nodes_idx.
__global__ __launch_bounds__(256) void scan3_kernel(
    int* __restrict__ offs, int* __restrict__ cursor,
    const int* __restrict__ bsum,
    const int* __restrict__ nodes, float* __restrict__ samp, int n)
{
    __shared__ int pref;
    if (threadIdx.x == 0) {
        int run = 0;
        const int lim = blockIdx.x >> 3;   // 8 scan3 blocks per scan1 block
        for (int i = 0; i < lim; ++i) run += bsum[i];
        pref = run;
    }
    __syncthreads();
    int i = blockIdx.x * 256 + threadIdx.x;
    if (i < n) {
        int v = offs[i] + pref;
        offs[i]   = v;
        cursor[i] = v;
        int nv = nodes[(size_t)i * 2 + 1];
        samp[i] = (nv > -1 && nv < N_NODE_C + 1) ? 1.f : 0.f;
    }
}

// Scatter full edge records {r_idx, rel, sub, e} in obj-sorted order.
__global__ __launch_bounds__(256) void scatter_kernel(
    const int* __restrict__ edges, int* __restrict__ cursor,
    int4* __restrict__ esorted, int E)
{
    int i = blockIdx.x * 256 + threadIdx.x;
    if (i < E) {
        int4 rec;
        rec.x = edges[(size_t)i * 6 + 0];
        rec.y = edges[(size_t)i * 6 + 2];
        rec.z = edges[(size_t)i * 6 + 4];
        rec.w = i;
        int obj = edges[(size_t)i * 6 + 5];
        int pos = atomicAdd(&cursor[obj], 1);
        esorted[pos] = rec;
    }
}

// ---------------------------------------------------------------------------
// Pull aggregation: one node per 16-lane group (4 nodes/wave), 8 cols/lane.
// 2-deep software pipeline: records kept two ahead, hsub row gathers (the
// only HBM-latency loads) one ahead — gather latency hides under the
// previous edge's compute. AGG_BF16: store agg row as bf16 (tier A+).
// ---------------------------------------------------------------------------
template <int AGG_BF16>
__global__ __launch_bounds__(256) void node_agg_kernel(
    const int4* __restrict__ esorted,
    const unsigned short* __restrict__ hsub,   // N x 256 bf16: [hidden | hsW]
    const float* __restrict__ relhr,           // RV x 256 f32: [hrW | rela]
    const float* __restrict__ qrW,             // B x 128 f32
    const float* __restrict__ walpha_w,
    const float* __restrict__ walpha_b,
    const int* __restrict__ deg,
    const int* __restrict__ offs,
    float* __restrict__ agg,                   // AGG_BF16=0: N x 128 f32
    unsigned short* __restrict__ aggb,         // AGG_BF16=1: N x 128 bf16
    float* __restrict__ alpha_out,
    int N)
{
    const int o = (blockIdx.x * 256 + threadIdx.x) >> 4;   // node = group id
    if (o >= N) return;
    const int l16 = threadIdx.x & 15;
    const int j   = l16 * 8;

    const int d = deg[o];
    const int s = offs[o];

    const float4 wwA = *(const float4*)&walpha_w[j];
    const float4 wwB = *(const float4*)&walpha_w[j + 4];
    const float  wb  = walpha_b[0];

    float4 accA = make_float4(0.f, 0.f, 0.f, 0.f);
    float4 accB = make_float4(0.f, 0.f, 0.f, 0.f);

    // Pipeline prologue: rec0 (+ its rows), rec1.
    int4 rec0 = make_int4(0, 0, 0, 0), rec1 = rec0;
    bf16x8 hb0 = {}, pb0 = {};
    if (d > 0) {
        rec0 = esorted[s];
        hb0 = *(const bf16x8*)&hsub[(size_t)rec0.z * 256 + j];
        pb0 = *(const bf16x8*)&hsub[(size_t)rec0.z * 256 + 128 + j];
        rec1 = (d > 1) ? esorted[s + 1] : rec0;
    }

    for (int k = 0; k < d; ++k) {
        // Prefetch stage: rec two ahead, rows one ahead.
        const int4 rec2 = (k + 2 < d) ? esorted[s + k + 2] : rec1;
        bf16x8 hb1 = hb0, pb1 = pb0;
        if (k + 1 < d) {
            hb1 = *(const bf16x8*)&hsub[(size_t)rec1.z * 256 + j];
            pb1 = *(const bf16x8*)&hsub[(size_t)rec1.z * 256 + 128 + j];
        }

        // Compute stage (rec0 / hb0 / pb0).
        const float* rr = &relhr[(size_t)rec0.y * 256];
        const float4 bA  = *(const float4*)&rr[j];
        const float4 bB  = *(const float4*)&rr[j + 4];
        const float4 rvA = *(const float4*)&rr[128 + j];
        const float4 rvB = *(const float4*)&rr[128 + j + 4];
        const float4 cA  = *(const float4*)&qrW[(size_t)rec0.x * DIM + j];
        const float4 cB  = *(const float4*)&qrW[(size_t)rec0.x * DIM + j + 4];

        float sdot =
            fmaxf(bf2f((unsigned short)pb0[0]) + bA.x + cA.x, 0.f) * wwA.x +
            fmaxf(bf2f((unsigned short)pb0[1]) + bA.y + cA.y, 0.f) * wwA.y +
            fmaxf(bf2f((unsigned short)pb0[2]) + bA.z + cA.z, 0.f) * wwA.z +
            fmaxf(bf2f((unsigned short)pb0[3]) + bA.w + cA.w, 0.f) * wwA.w +
            fmaxf(bf2f((unsigned short)pb0[4]) + bB.x + cB.x, 0.f) * wwB.x +
            fmaxf(bf2f((unsigned short)pb0[5]) + bB.y + cB.y, 0.f) * wwB.y +
            fmaxf(bf2f((unsigned short)pb0[6]) + bB.z + cB.z, 0.f) * wwB.z +
            fmaxf(bf2f((unsigned short)pb0[7]) + bB.w + cB.w, 0.f) * wwB.w;

#pragma unroll
        for (int off = 8; off >= 1; off >>= 1)
            sdot += __shfl_xor(sdot, off, 16);

        const float alpha =
            __builtin_amdgcn_rcpf(1.f + __expf(-(sdot + wb)));

        accA.x += alpha * (bf2f((unsigned short)hb0[0]) + rvA.x);
        accA.y += alpha * (bf2f((unsigned short)hb0[1]) + rvA.y);
        accA.z += alpha * (bf2f((unsigned short)hb0[2]) + rvA.z);
        accA.w += alpha * (bf2f((unsigned short)hb0[3]) + rvA.w);
        accB.x += alpha * (bf2f((unsigned short)hb0[4]) + rvB.x);
        accB.y += alpha * (bf2f((unsigned short)hb0[5]) + rvB.y);
        accB.z += alpha * (bf2f((unsigned short)hb0[6]) + rvB.z);
        accB.w += alpha * (bf2f((unsigned short)hb0[7]) + rvB.w);

        if (l16 == 0) alpha_out[rec0.w] = alpha;

        rec0 = rec1; rec1 = rec2; hb0 = hb1; pb0 = pb1;
    }

    if (AGG_BF16) {
        bf16x8 ob;
        ob[0] = (short)f2bf_rne(accA.x); ob[1] = (short)f2bf_rne(accA.y);
        ob[2] = (short)f2bf_rne(accA.z); ob[3] = (short)f2bf_rne(accA.w);
        ob[4] = (short)f2bf_rne(accB.x); ob[5] = (short)f2bf_rne(accB.y);
        ob[6] = (short)f2bf_rne(accB.z); ob[7] = (short)f2bf_rne(accB.w);
        *(bf16x8*)&aggb[(size_t)o * DIM + j] = ob;
    } else {
        *(float4*)&agg[(size_t)o * DIM + j]     = accA;
        *(float4*)&agg[(size_t)o * DIM + j + 4] = accB;
    }
}

// ---------------------------------------------------------------------------
// Tier-C fallback: push-style edge kernel (inline hs @ Ws), f32 atomics.
// ---------------------------------------------------------------------------
__global__ __launch_bounds__(256) void edge_kernel_fb(
    const int* __restrict__ edges,
    const float* __restrict__ hidden,
    const float* __restrict__ rela,
    const float* __restrict__ Ws,
    const float* __restrict__ qrW,
    const float* __restrict__ relhr,
    const float* __restrict__ walpha_w,
    const float* __restrict__ walpha_b,
    float* __restrict__ agg,
    float* __restrict__ alpha_out,
    int E)
{
    const int widx = threadIdx.x >> 6;
    const int lane = threadIdx.x & 63;
    const int e    = blockIdx.x * 4 + widx;
    const bool valid = (e < E);
    const int ec   = valid ? e : 0;

    const int r_idx = edges[(size_t)ec * 6 + 0];
    const int rel   = edges[(size_t)ec * 6 + 2];
    const int sub   = edges[(size_t)ec * 6 + 4];
    const int obj   = edges[(size_t)ec * 6 + 5];

    const int j = lane * 2;

    const float2 hv = *(const float2*)&hidden[(size_t)sub * DIM + j];
    const float2 rv = *(const float2*)&rela[(size_t)rel * DIM + j];

    __shared__ float hrow[4][DIM];
    *(float2*)&hrow[widx][j] = hv;
    __syncthreads();
    float p0 = 0.f, p1 = 0.f;
#pragma unroll 4
    for (int k = 0; k < DIM; ++k) {
        float hk  = hrow[widx][k];
        float2 w2 = *(const float2*)&Ws[k * DIM + j];
        p0 += hk * w2.x;
        p1 += hk * w2.y;
    }

    const float2 b2 = *(const float2*)&relhr[(size_t)rel * 256 + j];
    const float2 c2 = *(const float2*)&qrW[(size_t)r_idx * DIM + j];
    p0 = fmaxf(p0 + b2.x + c2.x, 0.f);
    p1 = fmaxf(p1 + b2.y + c2.y, 0.f);

    const float2 ww = *(const float2*)&walpha_w[j];
    float s = p0 * ww.x + p1 * ww.y;
#pragma unroll
    for (int off = 32; off >= 1; off >>= 1)
        s += __shfl_xor(s, off, 64);

    const float alpha = 1.f / (1.f + expf(-(s + walpha_b[0])));

    if (valid) {
        const float m0 = alpha * (hv.x + rv.x);
        const float m1 = alpha * (hv.y + rv.y);
        atomicAdd(&agg[(size_t)obj * DIM + j], m0);
        atomicAdd(&agg[(size_t)obj * DIM + j + 1], m1);
        if (lane == 0) alpha_out[e] = alpha;
    }
}

__global__ __launch_bounds__(256, 3) void gemm_n128(
    const float* A,
    const float* __restrict__ W,
    float* C,
    int M)
{
    __shared__ __align__(16) float Alds[64][DIM];
    __shared__ __align__(16) float Wlds[32][DIM];

    const int t    = threadIdx.x;
    const int row0 = blockIdx.x * 64;
    const int tx   = t & 31;
    const int ty   = t >> 5;

#pragma unroll
    for (int p = 0; p < 8; ++p) {
        int idx = p * 1024 + t * 4;
        int r   = idx >> 7;
        int c   = idx & 127;
        int gr  = row0 + r;
        if (gr >= M) gr = M - 1;
        *(float4*)&Alds[r][c] = *(const float4*)&A[(size_t)gr * DIM + c];
    }

    float acc[8][4] = {};

    for (int kk = 0; kk < 4; ++kk) {
        __syncthreads();
        {
            const float* Wg = W + (size_t)kk * 32 * DIM;
#pragma unroll
            for (int p = 0; p < 4; ++p) {
                int idx = p * 1024 + t * 4;
                *(float4*)&Wlds[idx >> 7][idx & 127] = *(const float4*)&Wg[idx];
            }
        }
        __syncthreads();

#pragma unroll 2
        for (int k4 = 0; k4 < 32; k4 += 4) {
            const float4 w0 = *(const float4*)&Wlds[k4 + 0][tx * 4];
            const float4 w1 = *(const float4*)&Wlds[k4 + 1][tx * 4];
            const float4 w2 = *(const float4*)&Wlds[k4 + 2][tx * 4];
            const float4 w3 = *(const float4*)&Wlds[k4 + 3][tx * 4];
#pragma unroll
            for (int i = 0; i < 8; ++i) {
                const float4 a = *(const float4*)&Alds[ty * 8 + i][kk * 32 + k4];
                acc[i][0] = fmaf(a.w, w3.x, fmaf(a.z, w2.x, fmaf(a.y, w1.x, fmaf(a.x, w0.x, acc[i][0]))));
                acc[i][1] = fmaf(a.w, w3.y, fmaf(a.z, w2.y, fmaf(a.y, w1.y, fmaf(a.x, w0.y, acc[i][1]))));
                acc[i][2] = fmaf(a.w, w3.z, fmaf(a.z, w2.z, fmaf(a.y, w1.z, fmaf(a.x, w0.z, acc[i][2]))));
                acc[i][3] = fmaf(a.w, w3.w, fmaf(a.z, w2.w, fmaf(a.y, w1.w, fmaf(a.x, w0.w, acc[i][3]))));
            }
        }
    }
    __syncthreads();

#pragma unroll
    for (int i = 0; i < 8; ++i) {
        int gr = row0 + ty * 8 + i;
        if (gr < M) {
            float4 v = make_float4(acc[i][0], acc[i][1], acc[i][2], acc[i][3]);
            *(float4*)&C[(size_t)gr * DIM + tx * 4] = v;
        }
    }
}

__global__ __launch_bounds__(256) void nodes_kernel(
    const int* __restrict__ nodes, float* __restrict__ out, int N)
{
    int i = blockIdx.x * 256 + threadIdx.x;
    if (i < N) {
        int v = nodes[(size_t)i * 2 + 1];
        out[i] = (v > -1 && v < N_NODE_C + 1) ? 1.f : 0.f;
    }
}

// ---------------------------------------------------------------------------
extern "C" void kernel_launch(void* const* d_in, const int* in_sizes, int n_in,
                              void* d_out, int out_size, void* d_ws, size_t ws_size,
                              hipStream_t stream)
{
    const int*   q_rel    = (const int*)d_in[1];
    const float* hidden   = (const float*)d_in[2];
    const int*   edges    = (const int*)d_in[3];
    const int*   nodes    = (const int*)d_in[4];
    const float* rela     = (const float*)d_in[5];
    const float* Ws       = (const float*)d_in[6];
    const float* Wr       = (const float*)d_in[7];
    const float* Wqr_w    = (const float*)d_in[8];
    const float* Wqr_b    = (const float*)d_in[9];
    const float* walpha_w = (const float*)d_in[10];
    const float* walpha_b = (const float*)d_in[11];
    const float* Wh       = (const float*)d_in[12];

    const int B  = in_sizes[1];
    const int N  = in_sizes[2] / DIM;
    const int E  = in_sizes[3] / 6;
    const int RV = in_sizes[5] / DIM;

    float* out       = (float*)d_out;
    float* agg       = out;                          // N*128 f32 (tier A)
    float* alpha_out = out + (size_t)N * DIM;        // E
    float* samp      = alpha_out + (size_t)E;        // N

    // Workspace layout (16-B alignment maintained in declaration order).
    char* p = (char*)d_ws;
    float* qrW   = (float*)p;     p += (size_t)B * DIM * sizeof(float);
    float* relhr = (float*)p;     p += (size_t)RV * 256 * sizeof(float);
    uint4* wpack_s = (uint4*)p;   p += 2048 * sizeof(uint4);
    uint4* wpack_h = (uint4*)p;   p += 2048 * sizeof(uint4);
    int4*  esorted = (int4*)p;    p += (size_t)E * sizeof(int4);
    unsigned short* hsub = (unsigned short*)p;
    p += (size_t)N * 256 * sizeof(unsigned short);
    const size_t pre_int_bytes = (size_t)(p - (char*)d_ws);
    const size_t int_bytes = ((size_t)3 * N + 128) * sizeof(int);

    const size_t need_A  = pre_int_bytes + int_bytes;
    const size_t need_Ap = need_A + (size_t)N * DIM * sizeof(unsigned short);

    const bool tierA  = (ws_size >= need_A);
    const bool tierAp = (ws_size >= need_Ap);

    int* deg = nullptr;
    int* offs = nullptr;
    int* cursor = nullptr;
    int* bsum = nullptr;
    unsigned short* aggb = nullptr;
    if (tierA) {
        char* q = (char*)d_ws + pre_int_bytes;
        deg    = (int*)q;
        offs   = deg + N;
        cursor = offs + N;
        bsum   = cursor + N;
        if (tierAp) aggb = (unsigned short*)(bsum + 128);
    }

    const int ZB = tierA ? (N + 127) / 128 : 0;
    setup_kernel<<<B + RV + 32 + ZB, 128, 0, stream>>>(
        q_rel, rela, Wqr_w, Wqr_b, Wr, Ws, Wh,
        qrW, relhr, wpack_s, wpack_h, deg, N, B, RV);

    if (tierA) {
        const int Nb = (N + 63) / 64;
        const int Hb = (E + 255) / 256;
        gemm_hist_kernel<<<Nb + Hb, 256, 0, stream>>>(
            hidden, wpack_s, hsub, N, edges, deg, E, Nb);

        const int nb = (N + 2047) / 2048;            // <= 128 (bsum capacity)
        scan1_kernel<<<nb, 256, 0, stream>>>(deg, offs, bsum, N);
        scan3_kernel<<<(N + 255) / 256, 256, 0, stream>>>(
            offs, cursor, bsum, nodes, samp, N);
        scatter_kernel<<<(E + 255) / 256, 256, 0, stream>>>(
            edges, cursor, esorted, E);

        if (tierAp) {
            node_agg_kernel<1><<<(N * 16 + 255) / 256, 256, 0, stream>>>(
                esorted, hsub, relhr, qrW, walpha_w, walpha_b,
                deg, offs, agg, aggb, alpha_out, N);
            gemm_final<1><<<(N + 63) / 64, 256, 0, stream>>>(
                aggb, wpack_h, out, N);
        } else {
            node_agg_kernel<0><<<(N * 16 + 255) / 256, 256, 0, stream>>>(
                esorted, hsub, relhr, qrW, walpha_w, walpha_b,
                deg, offs, agg, aggb, alpha_out, N);
            gemm_final<0><<<(N + 63) / 64, 256, 0, stream>>>(
                agg, wpack_h, out, N);
        }
    } else {
        // --- tier C fallback: push-style with atomics, fp32 GEMM ---
        hipMemsetAsync(agg, 0, (size_t)N * DIM * sizeof(float), stream);
        edge_kernel_fb<<<(E + 3) / 4, 256, 0, stream>>>(
            edges, hidden, rela, Ws, qrW, relhr, walpha_w, walpha_b,
            agg, alpha_out, E);
        gemm_n128<<<(N + 63) / 64, 256, 0, stream>>>(agg, Wh, out, N);
        nodes_kernel<<<(N + 255) / 256, 256, 0, stream>>>(nodes, samp, N);
    }
}

// Round 12
// 234.362 us; speedup vs baseline: 1.0825x; 1.0825x over previous
//
#include <hip/hip_runtime.h>
#include <hip/hip_bf16.h>
#include <math.h>

// Problem constants (from reference): D = ATTN = 128, N_NODE = 100000.
#define DIM 128
#define N_NODE_C 100000

typedef __attribute__((ext_vector_type(8))) short  bf16x8;
typedef __attribute__((ext_vector_type(4))) float  f32x4;

__device__ inline unsigned short f2bf_rne(float f) {
    unsigned u = __float_as_uint(f);
    return (unsigned short)((u + 0x7FFFu + ((u >> 16) & 1u)) >> 16);
}
__device__ inline float bf2f(unsigned short u) {
    return __uint_as_float(((unsigned)u) << 16);
}

// ---------------------------------------------------------------------------
// Fused setup kernel (128 threads/block):
//   blocks [0, B)            : qrW[b]   = rela[q_rel[b]] @ Wqr_w + Wqr_b
//   blocks [B, B+RV)         : relhr[r] = [ rela[r] @ Wr | rela[r] ]  (256 c)
//   blocks [B+RV, B+RV+32)   : pack Ws / Wh into MFMA B-fragment layout
//   blocks [B+RV+32, ...)    : zero deg[] (replaces hipMemsetAsync)
// ---------------------------------------------------------------------------
__global__ __launch_bounds__(128) void setup_kernel(
    const int* __restrict__ q_rel,
    const float* __restrict__ rela,
    const float* __restrict__ Wqr_w,
    const float* __restrict__ Wqr_b,
    const float* __restrict__ Wr,
    const float* __restrict__ Ws,
    const float* __restrict__ Wh,
    float* __restrict__ qrW,
    float* __restrict__ relhr,
    uint4* __restrict__ wpack_s,
    uint4* __restrict__ wpack_h,
    int* deg, int N,
    int B, int RV)
{
    const int blk = blockIdx.x;
    const int j   = threadIdx.x;

    if (blk < B + RV) {
        __shared__ float emb[DIM];
        const float* W;
        float* out;
        float bias = 0.f;
        int row;
        if (blk < B) {
            row  = q_rel[blk];
            W    = Wqr_w;
            out  = qrW + (size_t)blk * DIM;
            bias = Wqr_b[j];
        } else {
            row = blk - B;
            W   = Wr;
            out = relhr + (size_t)(blk - B) * 256;
        }
        emb[j] = rela[(size_t)row * DIM + j];
        __syncthreads();

        float acc = bias;
#pragma unroll 8
        for (int k = 0; k < DIM; ++k)
            acc += emb[k] * W[k * DIM + j];
        out[j] = acc;
        if (blk >= B)
            out[128 + j] = emb[j];      // rela copy: free (already in LDS)
        return;
    }

    if (blk < B + RV + 32) {
        // --- pack path ---
        const int pid = blk - (B + RV);          // 0..31
        const float* W = (pid < 16) ? Ws : Wh;
        uint4* dst     = (pid < 16) ? wpack_s : wpack_h;
        const int id   = (pid & 15) * 128 + j;   // 0..2047
        const int ct   = id >> 8;
        const int kb   = (id >> 6) & 3;
        const int lane = id & 63;
        const int col  = ct * 16 + (lane & 15);
        const int k0   = kb * 32 + (lane >> 4) * 8;

        unsigned v[4];
#pragma unroll
        for (int p = 0; p < 4; ++p) {
            unsigned lo = f2bf_rne(W[(size_t)(k0 + 2 * p)     * DIM + col]);
            unsigned hi = f2bf_rne(W[(size_t)(k0 + 2 * p + 1) * DIM + col]);
            v[p] = lo | (hi << 16);
        }
        dst[id] = make_uint4(v[0], v[1], v[2], v[3]);
        return;
    }

    // --- deg zeroing path ---
    if (deg) {
        int i = (blk - (B + RV + 32)) * 128 + j;
        if (i < N) deg[i] = 0;
    }
}

// ---------------------------------------------------------------------------
// Fused GEMM + histogram. Heterogeneous grid:
//   blocks [0, Nb)      : hsub[M x 256] bf16 = [ bf16(A) | A @ W ]
//   blocks [Nb, Nb+Hb)  : deg histogram of edges obj column.
// C/D layout (HW-verified): col = lane&15, row = (lane>>4)*4 + reg.
// ---------------------------------------------------------------------------
__global__ __launch_bounds__(256) void gemm_hist_kernel(
    const float* __restrict__ A, const uint4* __restrict__ Wpack,
    unsigned short* __restrict__ H, int M,
    const int* __restrict__ edges, int* __restrict__ deg, int E, int Nb)
{
    if ((int)blockIdx.x >= Nb) {
        int i = ((int)blockIdx.x - Nb) * 256 + threadIdx.x;
        if (i < E) atomicAdd(&deg[edges[(size_t)i * 6 + 5]], 1);
        return;
    }

    __shared__ uint4 wlds[2048];   // [ct][kb][lane], 32 KB
    const int t = threadIdx.x;
#pragma unroll
    for (int p = 0; p < 8; ++p)
        wlds[p * 256 + t] = Wpack[p * 256 + t];
    __syncthreads();

    const int wave = t >> 6;
    const int lane = t & 63;
    const int r    = lane & 15;
    const int g    = lane >> 4;
    const int row0 = blockIdx.x * 64 + wave * 16;

    int arow = row0 + r;
    if (arow >= M) arow = M - 1;
    const float* Ap = A + (size_t)arow * DIM + g * 8;

    bf16x8 afrag[4];
#pragma unroll
    for (int kb = 0; kb < 4; ++kb) {
        const float4 lo = *(const float4*)(Ap + kb * 32);
        const float4 hi = *(const float4*)(Ap + kb * 32 + 4);
        bf16x8 a;
        a[0] = (short)f2bf_rne(lo.x); a[1] = (short)f2bf_rne(lo.y);
        a[2] = (short)f2bf_rne(lo.z); a[3] = (short)f2bf_rne(lo.w);
        a[4] = (short)f2bf_rne(hi.x); a[5] = (short)f2bf_rne(hi.y);
        a[6] = (short)f2bf_rne(hi.z); a[7] = (short)f2bf_rne(hi.w);
        afrag[kb] = a;
    }

    // bf16(A) into cols 0..127 (free conversion).
#pragma unroll
    for (int kb = 0; kb < 4; ++kb)
        *(bf16x8*)&H[(size_t)arow * 256 + kb * 32 + g * 8] = afrag[kb];

#pragma unroll
    for (int ct = 0; ct < 8; ++ct) {
        f32x4 acc = {0.f, 0.f, 0.f, 0.f};
#pragma unroll
        for (int kb = 0; kb < 4; ++kb) {
            bf16x8 b = *(bf16x8*)&wlds[ct * 256 + kb * 64 + lane];
            acc = __builtin_amdgcn_mfma_f32_16x16x32_bf16(afrag[kb], b, acc, 0, 0, 0);
        }
        const int col = ct * 16 + r;
#pragma unroll
        for (int jj = 0; jj < 4; ++jj) {
            const int row = row0 + g * 4 + jj;
            if (row < M)
                H[(size_t)row * 256 + 128 + col] = f2bf_rne(acc[jj]);
        }
    }
}

// ---------------------------------------------------------------------------
// Final GEMM: C[M x 128] f32 = A(f32) @ Wh. In-place safe (C == A): each
// wave reads its own 16 A-rows through registers before storing them.
// ---------------------------------------------------------------------------
__global__ __launch_bounds__(256) void gemm_mfma_f32(
    const float* A, const uint4* __restrict__ Wpack, float* C, int M)
{
    __shared__ uint4 wlds[2048];
    const int t = threadIdx.x;
#pragma unroll
    for (int p = 0; p < 8; ++p)
        wlds[p * 256 + t] = Wpack[p * 256 + t];
    __syncthreads();

    const int wave = t >> 6;
    const int lane = t & 63;
    const int r    = lane & 15;
    const int g    = lane >> 4;
    const int row0 = blockIdx.x * 64 + wave * 16;

    int arow = row0 + r;
    if (arow >= M) arow = M - 1;
    const float* Ap = A + (size_t)arow * DIM + g * 8;

    bf16x8 afrag[4];
#pragma unroll
    for (int kb = 0; kb < 4; ++kb) {
        const float4 lo = *(const float4*)(Ap + kb * 32);
        const float4 hi = *(const float4*)(Ap + kb * 32 + 4);
        bf16x8 a;
        a[0] = (short)f2bf_rne(lo.x); a[1] = (short)f2bf_rne(lo.y);
        a[2] = (short)f2bf_rne(lo.z); a[3] = (short)f2bf_rne(lo.w);
        a[4] = (short)f2bf_rne(hi.x); a[5] = (short)f2bf_rne(hi.y);
        a[6] = (short)f2bf_rne(hi.z); a[7] = (short)f2bf_rne(hi.w);
        afrag[kb] = a;
    }

#pragma unroll
    for (int ct = 0; ct < 8; ++ct) {
        f32x4 acc = {0.f, 0.f, 0.f, 0.f};
#pragma unroll
        for (int kb = 0; kb < 4; ++kb) {
            bf16x8 b = *(bf16x8*)&wlds[ct * 256 + kb * 64 + lane];
            acc = __builtin_amdgcn_mfma_f32_16x16x32_bf16(afrag[kb], b, acc, 0, 0, 0);
        }
        const int col = ct * 16 + r;
#pragma unroll
        for (int jj = 0; jj < 4; ++jj) {
            const int row = row0 + g * 4 + jj;
            if (row < M)
                C[(size_t)row * DIM + col] = acc[jj];
        }
    }
}

// ---------------------------------------------------------------------------
// Sort scaffolding.
// ---------------------------------------------------------------------------
__global__ __launch_bounds__(256) void scan1_kernel(
    const int* __restrict__ in, int* __restrict__ out,
    int* __restrict__ bsum, int n)
{
    __shared__ int ts[256];
    const int tid  = threadIdx.x;
    const int base = blockIdx.x * 2048 + tid * 8;

    int v[8];
    int run = 0;
#pragma unroll
    for (int i = 0; i < 8; ++i) {
        int x = (base + i < n) ? in[base + i] : 0;
        v[i] = run;
        run += x;
    }
    ts[tid] = run;
    __syncthreads();
    for (int off = 1; off < 256; off <<= 1) {
        int x = (tid >= off) ? ts[tid - off] : 0;
        __syncthreads();
        ts[tid] += x;
        __syncthreads();
    }
    const int excl = ts[tid] - run;
#pragma unroll
    for (int i = 0; i < 8; ++i)
        if (base + i < n) out[base + i] = v[i] + excl;
    if (tid == 255) bsum[blockIdx.x] = ts[255];
}

// Adds cross-block prefix (bsum holds block totals), duplicates into cursor,
// and emits sampled_nodes_idx.
__global__ __launch_bounds__(256) void scan3_kernel(
    int* __restrict__ offs, int* __restrict__ cursor,
    const int* __restrict__ bsum,
    const int* __restrict__ nodes, float* __restrict__ samp, int n)
{
    __shared__ int pref;
    if (threadIdx.x == 0) {
        int run = 0;
        const int lim = blockIdx.x >> 3;   // 8 scan3 blocks per scan1 block
        for (int i = 0; i < lim; ++i) run += bsum[i];
        pref = run;
    }
    __syncthreads();
    int i = blockIdx.x * 256 + threadIdx.x;
    if (i < n) {
        int v = offs[i] + pref;
        offs[i]   = v;
        cursor[i] = v;
        int nv = nodes[(size_t)i * 2 + 1];
        samp[i] = (nv > -1 && nv < N_NODE_C + 1) ? 1.f : 0.f;
    }
}

// Scatter full edge records {r_idx, rel, sub, e} in obj-sorted order.
__global__ __launch_bounds__(256) void scatter_kernel(
    const int* __restrict__ edges, int* __restrict__ cursor,
    int4* __restrict__ esorted, int E)
{
    int i = blockIdx.x * 256 + threadIdx.x;
    if (i < E) {
        int4 rec;
        rec.x = edges[(size_t)i * 6 + 0];
        rec.y = edges[(size_t)i * 6 + 2];
        rec.z = edges[(size_t)i * 6 + 4];
        rec.w = i;
        int obj = edges[(size_t)i * 6 + 5];
        int pos = atomicAdd(&cursor[obj], 1);
        esorted[pos] = rec;
    }
}

// ---------------------------------------------------------------------------
// Per-edge compute shared by both node_agg paths.
// ---------------------------------------------------------------------------
__device__ inline void edge_compute(
    const int4 rec, const bf16x8 hb, const bf16x8 pb,
    const float* __restrict__ relhr, const float* __restrict__ qrW,
    const float4 wwA, const float4 wwB, const float wb,
    int j, int l16,
    float4& accA, float4& accB, float* __restrict__ alpha_out)
{
    const float* rr = &relhr[(size_t)rec.y * 256];
    const float4 bA  = *(const float4*)&rr[j];
    const float4 bB  = *(const float4*)&rr[j + 4];
    const float4 rvA = *(const float4*)&rr[128 + j];
    const float4 rvB = *(const float4*)&rr[128 + j + 4];
    const float4 cA  = *(const float4*)&qrW[(size_t)rec.x * DIM + j];
    const float4 cB  = *(const float4*)&qrW[(size_t)rec.x * DIM + j + 4];

    float sdot =
        fmaxf(bf2f((unsigned short)pb[0]) + bA.x + cA.x, 0.f) * wwA.x +
        fmaxf(bf2f((unsigned short)pb[1]) + bA.y + cA.y, 0.f) * wwA.y +
        fmaxf(bf2f((unsigned short)pb[2]) + bA.z + cA.z, 0.f) * wwA.z +
        fmaxf(bf2f((unsigned short)pb[3]) + bA.w + cA.w, 0.f) * wwA.w +
        fmaxf(bf2f((unsigned short)pb[4]) + bB.x + cB.x, 0.f) * wwB.x +
        fmaxf(bf2f((unsigned short)pb[5]) + bB.y + cB.y, 0.f) * wwB.y +
        fmaxf(bf2f((unsigned short)pb[6]) + bB.z + cB.z, 0.f) * wwB.z +
        fmaxf(bf2f((unsigned short)pb[7]) + bB.w + cB.w, 0.f) * wwB.w;

#pragma unroll
    for (int off = 8; off >= 1; off >>= 1)
        sdot += __shfl_xor(sdot, off, 16);

    const float alpha =
        __builtin_amdgcn_rcpf(1.f + __expf(-(sdot + wb)));

    accA.x += alpha * (bf2f((unsigned short)hb[0]) + rvA.x);
    accA.y += alpha * (bf2f((unsigned short)hb[1]) + rvA.y);
    accA.z += alpha * (bf2f((unsigned short)hb[2]) + rvA.z);
    accA.w += alpha * (bf2f((unsigned short)hb[3]) + rvA.w);
    accB.x += alpha * (bf2f((unsigned short)hb[4]) + rvB.x);
    accB.y += alpha * (bf2f((unsigned short)hb[5]) + rvB.y);
    accB.z += alpha * (bf2f((unsigned short)hb[6]) + rvB.z);
    accB.w += alpha * (bf2f((unsigned short)hb[7]) + rvB.w);

    if (l16 == 0) alpha_out[rec.w] = alpha;
}

// ---------------------------------------------------------------------------
// Pull aggregation: one node per 16-lane group (4 nodes/wave), 8 cols/lane.
// d <= 4 (95% of nodes, Poisson lambda=2): load all records then issue ALL
// row gathers back-to-back (independent) before any compute — one latency
// exposure instead of d serial ones. d > 4: serial loop w/ record prefetch.
// One clean 512 B f32 row store per node into d_out.
// ---------------------------------------------------------------------------
__global__ __launch_bounds__(256) void node_agg_kernel(
    const int4* __restrict__ esorted,
    const unsigned short* __restrict__ hsub,   // N x 256 bf16: [hidden | hsW]
    const float* __restrict__ relhr,           // RV x 256 f32: [hrW | rela]
    const float* __restrict__ qrW,             // B x 128 f32
    const float* __restrict__ walpha_w,
    const float* __restrict__ walpha_b,
    const int* __restrict__ deg,
    const int* __restrict__ offs,
    float* __restrict__ agg,
    float* __restrict__ alpha_out,
    int N)
{
    const int o = (blockIdx.x * 256 + threadIdx.x) >> 4;   // node = group id
    if (o >= N) return;
    const int l16 = threadIdx.x & 15;
    const int j   = l16 * 8;

    const int d = deg[o];
    const int s = offs[o];

    const float4 wwA = *(const float4*)&walpha_w[j];
    const float4 wwB = *(const float4*)&walpha_w[j + 4];
    const float  wb  = walpha_b[0];

    float4 accA = make_float4(0.f, 0.f, 0.f, 0.f);
    float4 accB = make_float4(0.f, 0.f, 0.f, 0.f);

    if (d > 0) {
        if (d <= 4) {
            // Batched path: all records, then ALL row gathers, then compute.
            int4 rec[4];
#pragma unroll
            for (int k = 0; k < 4; ++k)
                if (k < d) rec[k] = esorted[s + k];
            bf16x8 hb[4], pb[4];
#pragma unroll
            for (int k = 0; k < 4; ++k)
                if (k < d) {
                    hb[k] = *(const bf16x8*)&hsub[(size_t)rec[k].z * 256 + j];
                    pb[k] = *(const bf16x8*)&hsub[(size_t)rec[k].z * 256 + 128 + j];
                }
#pragma unroll
            for (int k = 0; k < 4; ++k)
                if (k < d)
                    edge_compute(rec[k], hb[k], pb[k], relhr, qrW,
                                 wwA, wwB, wb, j, l16, accA, accB, alpha_out);
        } else {
            // Serial path with 1-deep record prefetch.
            int4 rec = esorted[s];
            for (int k = 0; k < d; ++k) {
                const int4 nrec = (k + 1 < d) ? esorted[s + k + 1] : rec;
                const bf16x8 hb = *(const bf16x8*)&hsub[(size_t)rec.z * 256 + j];
                const bf16x8 pb = *(const bf16x8*)&hsub[(size_t)rec.z * 256 + 128 + j];
                edge_compute(rec, hb, pb, relhr, qrW,
                             wwA, wwB, wb, j, l16, accA, accB, alpha_out);
                rec = nrec;
            }
        }
    }

    *(float4*)&agg[(size_t)o * DIM + j]     = accA;
    *(float4*)&agg[(size_t)o * DIM + j + 4] = accB;
}

// ---------------------------------------------------------------------------
// Tier-C fallback: push-style edge kernel (inline hs @ Ws), f32 atomics.
// ---------------------------------------------------------------------------
__global__ __launch_bounds__(256) void edge_kernel_fb(
    const int* __restrict__ edges,
    const float* __restrict__ hidden,
    const float* __restrict__ rela,
    const float* __restrict__ Ws,
    const float* __restrict__ qrW,
    const float* __restrict__ relhr,
    const float* __restrict__ walpha_w,
    const float* __restrict__ walpha_b,
    float* __restrict__ agg,
    float* __restrict__ alpha_out,
    int E)
{
    const int widx = threadIdx.x >> 6;
    const int lane = threadIdx.x & 63;
    const int e    = blockIdx.x * 4 + widx;
    const bool valid = (e < E);
    const int ec   = valid ? e : 0;

    const int r_idx = edges[(size_t)ec * 6 + 0];
    const int rel   = edges[(size_t)ec * 6 + 2];
    const int sub   = edges[(size_t)ec * 6 + 4];
    const int obj   = edges[(size_t)ec * 6 + 5];

    const int j = lane * 2;

    const float2 hv = *(const float2*)&hidden[(size_t)sub * DIM + j];
    const float2 rv = *(const float2*)&rela[(size_t)rel * DIM + j];

    __shared__ float hrow[4][DIM];
    *(float2*)&hrow[widx][j] = hv;
    __syncthreads();
    float p0 = 0.f, p1 = 0.f;
#pragma unroll 4
    for (int k = 0; k < DIM; ++k) {
        float hk  = hrow[widx][k];
        float2 w2 = *(const float2*)&Ws[k * DIM + j];
        p0 += hk * w2.x;
        p1 += hk * w2.y;
    }

    const float2 b2 = *(const float2*)&relhr[(size_t)rel * 256 + j];
    const float2 c2 = *(const float2*)&qrW[(size_t)r_idx * DIM + j];
    p0 = fmaxf(p0 + b2.x + c2.x, 0.f);
    p1 = fmaxf(p1 + b2.y + c2.y, 0.f);

    const float2 ww = *(const float2*)&walpha_w[j];
    float s = p0 * ww.x + p1 * ww.y;
#pragma unroll
    for (int off = 32; off >= 1; off >>= 1)
        s += __shfl_xor(s, off, 64);

    const float alpha = 1.f / (1.f + expf(-(s + walpha_b[0])));

    if (valid) {
        const float m0 = alpha * (hv.x + rv.x);
        const float m1 = alpha * (hv.y + rv.y);
        atomicAdd(&agg[(size_t)obj * DIM + j], m0);
        atomicAdd(&agg[(size_t)obj * DIM + j + 1], m1);
        if (lane == 0) alpha_out[e] = alpha;
    }
}

__global__ __launch_bounds__(256, 3) void gemm_n128(
    const float* A,
    const float* __restrict__ W,
    float* C,
    int M)
{
    __shared__ __align__(16) float Alds[64][DIM];
    __shared__ __align__(16) float Wlds[32][DIM];

    const int t    = threadIdx.x;
    const int row0 = blockIdx.x * 64;
    const int tx   = t & 31;
    const int ty   = t >> 5;

#pragma unroll
    for (int p = 0; p < 8; ++p) {
        int idx = p * 1024 + t * 4;
        int r   = idx >> 7;
        int c   = idx & 127;
        int gr  = row0 + r;
        if (gr >= M) gr = M - 1;
        *(float4*)&Alds[r][c] = *(const float4*)&A[(size_t)gr * DIM + c];
    }

    float acc[8][4] = {};

    for (int kk = 0; kk < 4; ++kk) {
        __syncthreads();
        {
            const float* Wg = W + (size_t)kk * 32 * DIM;
#pragma unroll
            for (int p = 0; p < 4; ++p) {
                int idx = p * 1024 + t * 4;
                *(float4*)&Wlds[idx >> 7][idx & 127] = *(const float4*)&Wg[idx];
            }
        }
        __syncthreads();

#pragma unroll 2
        for (int k4 = 0; k4 < 32; k4 += 4) {
            const float4 w0 = *(const float4*)&Wlds[k4 + 0][tx * 4];
            const float4 w1 = *(const float4*)&Wlds[k4 + 1][tx * 4];
            const float4 w2 = *(const float4*)&Wlds[k4 + 2][tx * 4];
            const float4 w3 = *(const float4*)&Wlds[k4 + 3][tx * 4];
#pragma unroll
            for (int i = 0; i < 8; ++i) {
                const float4 a = *(const float4*)&Alds[ty * 8 + i][kk * 32 + k4];
                acc[i][0] = fmaf(a.w, w3.x, fmaf(a.z, w2.x, fmaf(a.y, w1.x, fmaf(a.x, w0.x, acc[i][0]))));
                acc[i][1] = fmaf(a.w, w3.y, fmaf(a.z, w2.y, fmaf(a.y, w1.y, fmaf(a.x, w0.y, acc[i][1]))));
                acc[i][2] = fmaf(a.w, w3.z, fmaf(a.z, w2.z, fmaf(a.y, w1.z, fmaf(a.x, w0.z, acc[i][2]))));
                acc[i][3] = fmaf(a.w, w3.w, fmaf(a.z, w2.w, fmaf(a.y, w1.w, fmaf(a.x, w0.w, acc[i][3]))));
            }
        }
    }
    __syncthreads();

#pragma unroll
    for (int i = 0; i < 8; ++i) {
        int gr = row0 + ty * 8 + i;
        if (gr < M) {
            float4 v = make_float4(acc[i][0], acc[i][1], acc[i][2], acc[i][3]);
            *(float4*)&C[(size_t)gr * DIM + tx * 4] = v;
        }
    }
}

__global__ __launch_bounds__(256) void nodes_kernel(
    const int* __restrict__ nodes, float* __restrict__ out, int N)
{
    int i = blockIdx.x * 256 + threadIdx.x;
    if (i < N) {
        int v = nodes[(size_t)i * 2 + 1];
        out[i] = (v > -1 && v < N_NODE_C + 1) ? 1.f : 0.f;
    }
}

// ---------------------------------------------------------------------------
extern "C" void kernel_launch(void* const* d_in, const int* in_sizes, int n_in,
                              void* d_out, int out_size, void* d_ws, size_t ws_size,
                              hipStream_t stream)
{
    const int*   q_rel    = (const int*)d_in[1];
    const float* hidden   = (const float*)d_in[2];
    const int*   edges    = (const int*)d_in[3];
    const int*   nodes    = (const int*)d_in[4];
    const float* rela     = (const float*)d_in[5];
    const float* Ws       = (const float*)d_in[6];
    const float* Wr       = (const float*)d_in[7];
    const float* Wqr_w    = (const float*)d_in[8];
    const float* Wqr_b    = (const float*)d_in[9];
    const float* walpha_w = (const float*)d_in[10];
    const float* walpha_b = (const float*)d_in[11];
    const float* Wh       = (const float*)d_in[12];

    const int B  = in_sizes[1];
    const int N  = in_sizes[2] / DIM;
    const int E  = in_sizes[3] / 6;
    const int RV = in_sizes[5] / DIM;

    float* out       = (float*)d_out;
    float* agg       = out;                          // N*128 f32
    float* alpha_out = out + (size_t)N * DIM;        // E
    float* samp      = alpha_out + (size_t)E;        // N

    // Workspace layout (16-B alignment maintained in declaration order).
    char* p = (char*)d_ws;
    float* qrW   = (float*)p;     p += (size_t)B * DIM * sizeof(float);
    float* relhr = (float*)p;     p += (size_t)RV * 256 * sizeof(float);
    uint4* wpack_s = (uint4*)p;   p += 2048 * sizeof(uint4);
    uint4* wpack_h = (uint4*)p;   p += 2048 * sizeof(uint4);
    int4*  esorted = (int4*)p;    p += (size_t)E * sizeof(int4);
    unsigned short* hsub = (unsigned short*)p;
    p += (size_t)N * 256 * sizeof(unsigned short);
    const size_t pre_int_bytes = (size_t)(p - (char*)d_ws);
    const size_t need_A = pre_int_bytes + ((size_t)3 * N + 128) * sizeof(int);

    const bool tierA = (ws_size >= need_A);

    int* deg = nullptr;
    int* offs = nullptr;
    int* cursor = nullptr;
    int* bsum = nullptr;
    if (tierA) {
        char* q = (char*)d_ws + pre_int_bytes;
        deg    = (int*)q;
        offs   = deg + N;
        cursor = offs + N;
        bsum   = cursor + N;
    }

    const int ZB = tierA ? (N + 127) / 128 : 0;
    setup_kernel<<<B + RV + 32 + ZB, 128, 0, stream>>>(
        q_rel, rela, Wqr_w, Wqr_b, Wr, Ws, Wh,
        qrW, relhr, wpack_s, wpack_h, deg, N, B, RV);

    if (tierA) {
        const int Nb = (N + 63) / 64;
        const int Hb = (E + 255) / 256;
        gemm_hist_kernel<<<Nb + Hb, 256, 0, stream>>>(
            hidden, wpack_s, hsub, N, edges, deg, E, Nb);

        const int nb = (N + 2047) / 2048;            // <= 128 (bsum capacity)
        scan1_kernel<<<nb, 256, 0, stream>>>(deg, offs, bsum, N);
        scan3_kernel<<<(N + 255) / 256, 256, 0, stream>>>(
            offs, cursor, bsum, nodes, samp, N);
        scatter_kernel<<<(E + 255) / 256, 256, 0, stream>>>(
            edges, cursor, esorted, E);

        node_agg_kernel<<<(N * 16 + 255) / 256, 256, 0, stream>>>(
            esorted, hsub, relhr, qrW, walpha_w, walpha_b,
            deg, offs, agg, alpha_out, N);

        // hidden_new = agg @ Wh, in place over d_out[0 : N*128].
        gemm_mfma_f32<<<(N + 63) / 64, 256, 0, stream>>>(agg, wpack_h, out, N);
    } else {
        // --- tier C fallback: push-style with atomics, fp32 GEMM ---
        hipMemsetAsync(agg, 0, (size_t)N * DIM * sizeof(float), stream);
        edge_kernel_fb<<<(E + 3) / 4, 256, 0, stream>>>(
            edges, hidden, rela, Ws, qrW, relhr, walpha_w, walpha_b,
            agg, alpha_out, E);
        gemm_n128<<<(N + 63) / 64, 256, 0, stream>>>(agg, Wh, out, N);
        nodes_kernel<<<(N + 255) / 256, 256, 0, stream>>>(nodes, samp, N);
    }
}

// Round 13
// 210.399 us; speedup vs baseline: 1.2058x; 1.1139x over previous
//
#include <hip/hip_runtime.h>
#include <hip/hip_bf16.h>
#include <math.h>

// Problem constants (from reference): D = ATTN = 128, N_NODE = 100000.
#define DIM 128
#define N_NODE_C 100000

typedef __attribute__((ext_vector_type(8))) short  bf16x8;
typedef __attribute__((ext_vector_type(4))) float  f32x4;

__device__ inline unsigned short f2bf_rne(float f) {
    unsigned u = __float_as_uint(f);
    return (unsigned short)((u + 0x7FFFu + ((u >> 16) & 1u)) >> 16);
}
__device__ inline float bf2f(unsigned short u) {
    return __uint_as_float(((unsigned)u) << 16);
}

// ---------------------------------------------------------------------------
// Fused setup kernel (128 threads/block):
//   blocks [0, B)            : qrW[b]   = rela[q_rel[b]] @ Wqr_w + Wqr_b
//   blocks [B, B+RV)         : relhr[r] = [ rela[r] @ Wr | rela[r] ]  (256 c)
//   blocks [B+RV, B+RV+32)   : pack Ws / Wh into MFMA B-fragment layout
//   blocks [B+RV+32, ...)    : zero deg[] (replaces hipMemsetAsync)
// ---------------------------------------------------------------------------
__global__ __launch_bounds__(128) void setup_kernel(
    const int* __restrict__ q_rel,
    const float* __restrict__ rela,
    const float* __restrict__ Wqr_w,
    const float* __restrict__ Wqr_b,
    const float* __restrict__ Wr,
    const float* __restrict__ Ws,
    const float* __restrict__ Wh,
    float* __restrict__ qrW,
    float* __restrict__ relhr,
    uint4* __restrict__ wpack_s,
    uint4* __restrict__ wpack_h,
    int* deg, int N,
    int B, int RV)
{
    const int blk = blockIdx.x;
    const int j   = threadIdx.x;

    if (blk < B + RV) {
        __shared__ float emb[DIM];
        const float* W;
        float* out;
        float bias = 0.f;
        int row;
        if (blk < B) {
            row  = q_rel[blk];
            W    = Wqr_w;
            out  = qrW + (size_t)blk * DIM;
            bias = Wqr_b[j];
        } else {
            row = blk - B;
            W   = Wr;
            out = relhr + (size_t)(blk - B) * 256;
        }
        emb[j] = rela[(size_t)row * DIM + j];
        __syncthreads();

        float acc = bias;
#pragma unroll 8
        for (int k = 0; k < DIM; ++k)
            acc += emb[k] * W[k * DIM + j];
        out[j] = acc;
        if (blk >= B)
            out[128 + j] = emb[j];      // rela copy: free (already in LDS)
        return;
    }

    if (blk < B + RV + 32) {
        // --- pack path ---
        const int pid = blk - (B + RV);          // 0..31
        const float* W = (pid < 16) ? Ws : Wh;
        uint4* dst     = (pid < 16) ? wpack_s : wpack_h;
        const int id   = (pid & 15) * 128 + j;   // 0..2047
        const int ct   = id >> 8;
        const int kb   = (id >> 6) & 3;
        const int lane = id & 63;
        const int col  = ct * 16 + (lane & 15);
        const int k0   = kb * 32 + (lane >> 4) * 8;

        unsigned v[4];
#pragma unroll
        for (int p = 0; p < 4; ++p) {
            unsigned lo = f2bf_rne(W[(size_t)(k0 + 2 * p)     * DIM + col]);
            unsigned hi = f2bf_rne(W[(size_t)(k0 + 2 * p + 1) * DIM + col]);
            v[p] = lo | (hi << 16);
        }
        dst[id] = make_uint4(v[0], v[1], v[2], v[3]);
        return;
    }

    // --- deg zeroing path ---
    if (deg) {
        int i = (blk - (B + RV + 32)) * 128 + j;
        if (i < N) deg[i] = 0;
    }
}

// ---------------------------------------------------------------------------
// Fused GEMM + histogram. Heterogeneous grid:
//   blocks [0, Nb)      : hsub[M x 256] bf16 = [ bf16(A) | A @ W ]
//   blocks [Nb, Nb+Hb)  : deg histogram of edges obj column.
// C/D layout (HW-verified): col = lane&15, row = (lane>>4)*4 + reg.
// ---------------------------------------------------------------------------
__global__ __launch_bounds__(256) void gemm_hist_kernel(
    const float* __restrict__ A, const uint4* __restrict__ Wpack,
    unsigned short* __restrict__ H, int M,
    const int* __restrict__ edges, int* __restrict__ deg, int E, int Nb)
{
    if ((int)blockIdx.x >= Nb) {
        int i = ((int)blockIdx.x - Nb) * 256 + threadIdx.x;
        if (i < E) atomicAdd(&deg[edges[(size_t)i * 6 + 5]], 1);
        return;
    }

    __shared__ uint4 wlds[2048];   // [ct][kb][lane], 32 KB
    const int t = threadIdx.x;
#pragma unroll
    for (int p = 0; p < 8; ++p)
        wlds[p * 256 + t] = Wpack[p * 256 + t];
    __syncthreads();

    const int wave = t >> 6;
    const int lane = t & 63;
    const int r    = lane & 15;
    const int g    = lane >> 4;
    const int row0 = blockIdx.x * 64 + wave * 16;

    int arow = row0 + r;
    if (arow >= M) arow = M - 1;
    const float* Ap = A + (size_t)arow * DIM + g * 8;

    bf16x8 afrag[4];
#pragma unroll
    for (int kb = 0; kb < 4; ++kb) {
        const float4 lo = *(const float4*)(Ap + kb * 32);
        const float4 hi = *(const float4*)(Ap + kb * 32 + 4);
        bf16x8 a;
        a[0] = (short)f2bf_rne(lo.x); a[1] = (short)f2bf_rne(lo.y);
        a[2] = (short)f2bf_rne(lo.z); a[3] = (short)f2bf_rne(lo.w);
        a[4] = (short)f2bf_rne(hi.x); a[5] = (short)f2bf_rne(hi.y);
        a[6] = (short)f2bf_rne(hi.z); a[7] = (short)f2bf_rne(hi.w);
        afrag[kb] = a;
    }

    // bf16(A) into cols 0..127 (free conversion).
#pragma unroll
    for (int kb = 0; kb < 4; ++kb)
        *(bf16x8*)&H[(size_t)arow * 256 + kb * 32 + g * 8] = afrag[kb];

#pragma unroll
    for (int ct = 0; ct < 8; ++ct) {
        f32x4 acc = {0.f, 0.f, 0.f, 0.f};
#pragma unroll
        for (int kb = 0; kb < 4; ++kb) {
            bf16x8 b = *(bf16x8*)&wlds[ct * 256 + kb * 64 + lane];
            acc = __builtin_amdgcn_mfma_f32_16x16x32_bf16(afrag[kb], b, acc, 0, 0, 0);
        }
        const int col = ct * 16 + r;
#pragma unroll
        for (int jj = 0; jj < 4; ++jj) {
            const int row = row0 + g * 4 + jj;
            if (row < M)
                H[(size_t)row * 256 + 128 + col] = f2bf_rne(acc[jj]);
        }
    }
}

// ---------------------------------------------------------------------------
// Sort scaffolding.
// ---------------------------------------------------------------------------
__global__ __launch_bounds__(256) void scan1_kernel(
    const int* __restrict__ in, int* __restrict__ out,
    int* __restrict__ bsum, int n)
{
    __shared__ int ts[256];
    const int tid  = threadIdx.x;
    const int base = blockIdx.x * 2048 + tid * 8;

    int v[8];
    int run = 0;
#pragma unroll
    for (int i = 0; i < 8; ++i) {
        int x = (base + i < n) ? in[base + i] : 0;
        v[i] = run;
        run += x;
    }
    ts[tid] = run;
    __syncthreads();
    for (int off = 1; off < 256; off <<= 1) {
        int x = (tid >= off) ? ts[tid - off] : 0;
        __syncthreads();
        ts[tid] += x;
        __syncthreads();
    }
    const int excl = ts[tid] - run;
#pragma unroll
    for (int i = 0; i < 8; ++i)
        if (base + i < n) out[base + i] = v[i] + excl;
    if (tid == 255) bsum[blockIdx.x] = ts[255];
}

// Adds cross-block prefix (bsum holds block totals), duplicates into cursor,
// and emits sampled_nodes_idx.
__global__ __launch_bounds__(256) void scan3_kernel(
    int* __restrict__ offs, int* __restrict__ cursor,
    const int* __restrict__ bsum,
    const int* __restrict__ nodes, float* __restrict__ samp, int n)
{
    __shared__ int pref;
    if (threadIdx.x == 0) {
        int run = 0;
        const int lim = blockIdx.x >> 3;   // 8 scan3 blocks per scan1 block
        for (int i = 0; i < lim; ++i) run += bsum[i];
        pref = run;
    }
    __syncthreads();
    int i = blockIdx.x * 256 + threadIdx.x;
    if (i < n) {
        int v = offs[i] + pref;
        offs[i]   = v;
        cursor[i] = v;
        int nv = nodes[(size_t)i * 2 + 1];
        samp[i] = (nv > -1 && nv < N_NODE_C + 1) ? 1.f : 0.f;
    }
}

// Scatter full edge records {r_idx, rel, sub, e} in obj-sorted order.
__global__ __launch_bounds__(256) void scatter_kernel(
    const int* __restrict__ edges, int* __restrict__ cursor,
    int4* __restrict__ esorted, int E)
{
    int i = blockIdx.x * 256 + threadIdx.x;
    if (i < E) {
        int4 rec;
        rec.x = edges[(size_t)i * 6 + 0];
        rec.y = edges[(size_t)i * 6 + 2];
        rec.z = edges[(size_t)i * 6 + 4];
        rec.w = i;
        int obj = edges[(size_t)i * 6 + 5];
        int pos = atomicAdd(&cursor[obj], 1);
        esorted[pos] = rec;
    }
}

// ---------------------------------------------------------------------------
// Per-edge compute (shared).
// ---------------------------------------------------------------------------
__device__ inline void edge_compute(
    const int4 rec, const bf16x8 hb, const bf16x8 pb,
    const float* __restrict__ relhr, const float* __restrict__ qrW,
    const float4 wwA, const float4 wwB, const float wb,
    int j, int l16,
    float4& accA, float4& accB, float* __restrict__ alpha_out)
{
    const float* rr = &relhr[(size_t)rec.y * 256];
    const float4 bA  = *(const float4*)&rr[j];
    const float4 bB  = *(const float4*)&rr[j + 4];
    const float4 rvA = *(const float4*)&rr[128 + j];
    const float4 rvB = *(const float4*)&rr[128 + j + 4];
    const float4 cA  = *(const float4*)&qrW[(size_t)rec.x * DIM + j];
    const float4 cB  = *(const float4*)&qrW[(size_t)rec.x * DIM + j + 4];

    float sdot =
        fmaxf(bf2f((unsigned short)pb[0]) + bA.x + cA.x, 0.f) * wwA.x +
        fmaxf(bf2f((unsigned short)pb[1]) + bA.y + cA.y, 0.f) * wwA.y +
        fmaxf(bf2f((unsigned short)pb[2]) + bA.z + cA.z, 0.f) * wwA.z +
        fmaxf(bf2f((unsigned short)pb[3]) + bA.w + cA.w, 0.f) * wwA.w +
        fmaxf(bf2f((unsigned short)pb[4]) + bB.x + cB.x, 0.f) * wwB.x +
        fmaxf(bf2f((unsigned short)pb[5]) + bB.y + cB.y, 0.f) * wwB.y +
        fmaxf(bf2f((unsigned short)pb[6]) + bB.z + cB.z, 0.f) * wwB.z +
        fmaxf(bf2f((unsigned short)pb[7]) + bB.w + cB.w, 0.f) * wwB.w;

#pragma unroll
    for (int off = 8; off >= 1; off >>= 1)
        sdot += __shfl_xor(sdot, off, 16);

    const float alpha =
        __builtin_amdgcn_rcpf(1.f + __expf(-(sdot + wb)));

    accA.x += alpha * (bf2f((unsigned short)hb[0]) + rvA.x);
    accA.y += alpha * (bf2f((unsigned short)hb[1]) + rvA.y);
    accA.z += alpha * (bf2f((unsigned short)hb[2]) + rvA.z);
    accA.w += alpha * (bf2f((unsigned short)hb[3]) + rvA.w);
    accB.x += alpha * (bf2f((unsigned short)hb[4]) + rvB.x);
    accB.y += alpha * (bf2f((unsigned short)hb[5]) + rvB.y);
    accB.z += alpha * (bf2f((unsigned short)hb[6]) + rvB.z);
    accB.w += alpha * (bf2f((unsigned short)hb[7]) + rvB.w);

    if (l16 == 0) alpha_out[rec.w] = alpha;
}

// ---------------------------------------------------------------------------
// Fused pull-aggregation + final GEMM.
// Phase 1 (round-10 structure): one node per 16-lane group (16 nodes/block),
//   serial edge walk with 1-deep record prefetch, acc in registers.
// Phase 2: acc rows -> LDS tile (bf16, padded), __syncthreads, then the
//   block's 4 waves compute tile[16x128] @ Wh[128x128] via MFMA (wave w owns
//   col-tiles 2w, 2w+1) and store hidden_new f32 rows directly to d_out.
// bf16 conversion of agg matches what the standalone GEMM did to its A input,
// so numerics are unchanged. Eliminates the separate gemm_final dispatch
// (102 MB write + 102 MB read + launch).
// ---------------------------------------------------------------------------
__global__ __launch_bounds__(256) void node_agg_fused(
    const int4* __restrict__ esorted,
    const unsigned short* __restrict__ hsub,   // N x 256 bf16: [hidden | hsW]
    const float* __restrict__ relhr,           // RV x 256 f32: [hrW | rela]
    const float* __restrict__ qrW,             // B x 128 f32
    const float* __restrict__ walpha_w,
    const float* __restrict__ walpha_b,
    const int* __restrict__ deg,
    const int* __restrict__ offs,
    const uint4* __restrict__ wpack_h,
    float* __restrict__ outC,                  // N x 128 f32 (hidden_new)
    float* __restrict__ alpha_out,
    int N)
{
    __shared__ unsigned short tile[16][136];   // padded: +8 bf16 per row
    __shared__ uint4 wlds[2048];               // Wh pack, 32 KB

    const int t = threadIdx.x;
#pragma unroll
    for (int p = 0; p < 8; ++p)
        wlds[p * 256 + t] = wpack_h[p * 256 + t];

    const int g16 = t >> 4;                    // group 0..15 = local node
    const int l16 = t & 15;
    const int j   = l16 * 8;
    const int o   = blockIdx.x * 16 + g16;

    float4 accA = make_float4(0.f, 0.f, 0.f, 0.f);
    float4 accB = make_float4(0.f, 0.f, 0.f, 0.f);

    if (o < N) {
        const int d = deg[o];
        const int s = offs[o];
        if (d > 0) {
            const float4 wwA = *(const float4*)&walpha_w[j];
            const float4 wwB = *(const float4*)&walpha_w[j + 4];
            const float  wb  = walpha_b[0];

            int4 rec = esorted[s];
            for (int k = 0; k < d; ++k) {
                const int4 nrec = (k + 1 < d) ? esorted[s + k + 1] : rec;
                const bf16x8 hb = *(const bf16x8*)&hsub[(size_t)rec.z * 256 + j];
                const bf16x8 pb = *(const bf16x8*)&hsub[(size_t)rec.z * 256 + 128 + j];
                edge_compute(rec, hb, pb, relhr, qrW,
                             wwA, wwB, wb, j, l16, accA, accB, alpha_out);
                rec = nrec;
            }
        }
    }

    // Phase 1 -> LDS (bf16), exactly the rounding the standalone GEMM applied.
    {
        bf16x8 ob;
        ob[0] = (short)f2bf_rne(accA.x); ob[1] = (short)f2bf_rne(accA.y);
        ob[2] = (short)f2bf_rne(accA.z); ob[3] = (short)f2bf_rne(accA.w);
        ob[4] = (short)f2bf_rne(accB.x); ob[5] = (short)f2bf_rne(accB.y);
        ob[6] = (short)f2bf_rne(accB.z); ob[7] = (short)f2bf_rne(accB.w);
        *(bf16x8*)&tile[g16][j] = ob;
    }
    __syncthreads();

    // Phase 2: 16x128 tile @ Wh. All 4 waves share the A fragment; wave w
    // computes col-tiles ct = 2w, 2w+1.
    const int wave = t >> 6;
    const int lane = t & 63;
    const int r    = lane & 15;
    const int g    = lane >> 4;

    bf16x8 afrag[4];
#pragma unroll
    for (int kb = 0; kb < 4; ++kb)
        afrag[kb] = *(const bf16x8*)&tile[r][kb * 32 + g * 8];

#pragma unroll
    for (int cti = 0; cti < 2; ++cti) {
        const int ct = wave * 2 + cti;
        f32x4 acc = {0.f, 0.f, 0.f, 0.f};
#pragma unroll
        for (int kb = 0; kb < 4; ++kb) {
            bf16x8 b = *(bf16x8*)&wlds[ct * 256 + kb * 64 + lane];
            acc = __builtin_amdgcn_mfma_f32_16x16x32_bf16(afrag[kb], b, acc, 0, 0, 0);
        }
        const int col = ct * 16 + r;
#pragma unroll
        for (int jj = 0; jj < 4; ++jj) {
            const int row = blockIdx.x * 16 + g * 4 + jj;
            if (row < N)
                outC[(size_t)row * DIM + col] = acc[jj];
        }
    }
}

// ---------------------------------------------------------------------------
// Tier-C fallback: push-style edge kernel (inline hs @ Ws), f32 atomics.
// ---------------------------------------------------------------------------
__global__ __launch_bounds__(256) void edge_kernel_fb(
    const int* __restrict__ edges,
    const float* __restrict__ hidden,
    const float* __restrict__ rela,
    const float* __restrict__ Ws,
    const float* __restrict__ qrW,
    const float* __restrict__ relhr,
    const float* __restrict__ walpha_w,
    const float* __restrict__ walpha_b,
    float* __restrict__ agg,
    float* __restrict__ alpha_out,
    int E)
{
    const int widx = threadIdx.x >> 6;
    const int lane = threadIdx.x & 63;
    const int e    = blockIdx.x * 4 + widx;
    const bool valid = (e < E);
    const int ec   = valid ? e : 0;

    const int r_idx = edges[(size_t)ec * 6 + 0];
    const int rel   = edges[(size_t)ec * 6 + 2];
    const int sub   = edges[(size_t)ec * 6 + 4];
    const int obj   = edges[(size_t)ec * 6 + 5];

    const int j = lane * 2;

    const float2 hv = *(const float2*)&hidden[(size_t)sub * DIM + j];
    const float2 rv = *(const float2*)&rela[(size_t)rel * DIM + j];

    __shared__ float hrow[4][DIM];
    *(float2*)&hrow[widx][j] = hv;
    __syncthreads();
    float p0 = 0.f, p1 = 0.f;
#pragma unroll 4
    for (int k = 0; k < DIM; ++k) {
        float hk  = hrow[widx][k];
        float2 w2 = *(const float2*)&Ws[k * DIM + j];
        p0 += hk * w2.x;
        p1 += hk * w2.y;
    }

    const float2 b2 = *(const float2*)&relhr[(size_t)rel * 256 + j];
    const float2 c2 = *(const float2*)&qrW[(size_t)r_idx * DIM + j];
    p0 = fmaxf(p0 + b2.x + c2.x, 0.f);
    p1 = fmaxf(p1 + b2.y + c2.y, 0.f);

    const float2 ww = *(const float2*)&walpha_w[j];
    float s = p0 * ww.x + p1 * ww.y;
#pragma unroll
    for (int off = 32; off >= 1; off >>= 1)
        s += __shfl_xor(s, off, 64);

    const float alpha = 1.f / (1.f + expf(-(s + walpha_b[0])));

    if (valid) {
        const float m0 = alpha * (hv.x + rv.x);
        const float m1 = alpha * (hv.y + rv.y);
        atomicAdd(&agg[(size_t)obj * DIM + j], m0);
        atomicAdd(&agg[(size_t)obj * DIM + j + 1], m1);
        if (lane == 0) alpha_out[e] = alpha;
    }
}

__global__ __launch_bounds__(256, 3) void gemm_n128(
    const float* A,
    const float* __restrict__ W,
    float* C,
    int M)
{
    __shared__ __align__(16) float Alds[64][DIM];
    __shared__ __align__(16) float Wlds[32][DIM];

    const int t    = threadIdx.x;
    const int row0 = blockIdx.x * 64;
    const int tx   = t & 31;
    const int ty   = t >> 5;

#pragma unroll
    for (int p = 0; p < 8; ++p) {
        int idx = p * 1024 + t * 4;
        int r   = idx >> 7;
        int c   = idx & 127;
        int gr  = row0 + r;
        if (gr >= M) gr = M - 1;
        *(float4*)&Alds[r][c] = *(const float4*)&A[(size_t)gr * DIM + c];
    }

    float acc[8][4] = {};

    for (int kk = 0; kk < 4; ++kk) {
        __syncthreads();
        {
            const float* Wg = W + (size_t)kk * 32 * DIM;
#pragma unroll
            for (int p = 0; p < 4; ++p) {
                int idx = p * 1024 + t * 4;
                *(float4*)&Wlds[idx >> 7][idx & 127] = *(const float4*)&Wg[idx];
            }
        }
        __syncthreads();

#pragma unroll 2
        for (int k4 = 0; k4 < 32; k4 += 4) {
            const float4 w0 = *(const float4*)&Wlds[k4 + 0][tx * 4];
            const float4 w1 = *(const float4*)&Wlds[k4 + 1][tx * 4];
            const float4 w2 = *(const float4*)&Wlds[k4 + 2][tx * 4];
            const float4 w3 = *(const float4*)&Wlds[k4 + 3][tx * 4];
#pragma unroll
            for (int i = 0; i < 8; ++i) {
                const float4 a = *(const float4*)&Alds[ty * 8 + i][kk * 32 + k4];
                acc[i][0] = fmaf(a.w, w3.x, fmaf(a.z, w2.x, fmaf(a.y, w1.x, fmaf(a.x, w0.x, acc[i][0]))));
                acc[i][1] = fmaf(a.w, w3.y, fmaf(a.z, w2.y, fmaf(a.y, w1.y, fmaf(a.x, w0.y, acc[i][1]))));
                acc[i][2] = fmaf(a.w, w3.z, fmaf(a.z, w2.z, fmaf(a.y, w1.z, fmaf(a.x, w0.z, acc[i][2]))));
                acc[i][3] = fmaf(a.w, w3.w, fmaf(a.z, w2.w, fmaf(a.y, w1.w, fmaf(a.x, w0.w, acc[i][3]))));
            }
        }
    }
    __syncthreads();

#pragma unroll
    for (int i = 0; i < 8; ++i) {
        int gr = row0 + ty * 8 + i;
        if (gr < M) {
            float4 v = make_float4(acc[i][0], acc[i][1], acc[i][2], acc[i][3]);
            *(float4*)&C[(size_t)gr * DIM + tx * 4] = v;
        }
    }
}

__global__ __launch_bounds__(256) void nodes_kernel(
    const int* __restrict__ nodes, float* __restrict__ out, int N)
{
    int i = blockIdx.x * 256 + threadIdx.x;
    if (i < N) {
        int v = nodes[(size_t)i * 2 + 1];
        out[i] = (v > -1 && v < N_NODE_C + 1) ? 1.f : 0.f;
    }
}

// ---------------------------------------------------------------------------
extern "C" void kernel_launch(void* const* d_in, const int* in_sizes, int n_in,
                              void* d_out, int out_size, void* d_ws, size_t ws_size,
                              hipStream_t stream)
{
    const int*   q_rel    = (const int*)d_in[1];
    const float* hidden   = (const float*)d_in[2];
    const int*   edges    = (const int*)d_in[3];
    const int*   nodes    = (const int*)d_in[4];
    const float* rela     = (const float*)d_in[5];
    const float* Ws       = (const float*)d_in[6];
    const float* Wr       = (const float*)d_in[7];
    const float* Wqr_w    = (const float*)d_in[8];
    const float* Wqr_b    = (const float*)d_in[9];
    const float* walpha_w = (const float*)d_in[10];
    const float* walpha_b = (const float*)d_in[11];
    const float* Wh       = (const float*)d_in[12];

    const int B  = in_sizes[1];
    const int N  = in_sizes[2] / DIM;
    const int E  = in_sizes[3] / 6;
    const int RV = in_sizes[5] / DIM;

    float* out       = (float*)d_out;
    float* hidnew    = out;                          // N*128 f32
    float* alpha_out = out + (size_t)N * DIM;        // E
    float* samp      = alpha_out + (size_t)E;        // N

    // Workspace layout (16-B alignment maintained in declaration order).
    char* p = (char*)d_ws;
    float* qrW   = (float*)p;     p += (size_t)B * DIM * sizeof(float);
    float* relhr = (float*)p;     p += (size_t)RV * 256 * sizeof(float);
    uint4* wpack_s = (uint4*)p;   p += 2048 * sizeof(uint4);
    uint4* wpack_h = (uint4*)p;   p += 2048 * sizeof(uint4);
    int4*  esorted = (int4*)p;    p += (size_t)E * sizeof(int4);
    unsigned short* hsub = (unsigned short*)p;
    p += (size_t)N * 256 * sizeof(unsigned short);
    const size_t pre_int_bytes = (size_t)(p - (char*)d_ws);
    const size_t need_A = pre_int_bytes + ((size_t)3 * N + 128) * sizeof(int);

    const bool tierA = (ws_size >= need_A);

    int* deg = nullptr;
    int* offs = nullptr;
    int* cursor = nullptr;
    int* bsum = nullptr;
    if (tierA) {
        char* q = (char*)d_ws + pre_int_bytes;
        deg    = (int*)q;
        offs   = deg + N;
        cursor = offs + N;
        bsum   = cursor + N;
    }

    const int ZB = tierA ? (N + 127) / 128 : 0;
    setup_kernel<<<B + RV + 32 + ZB, 128, 0, stream>>>(
        q_rel, rela, Wqr_w, Wqr_b, Wr, Ws, Wh,
        qrW, relhr, wpack_s, wpack_h, deg, N, B, RV);

    if (tierA) {
        const int Nb = (N + 63) / 64;
        const int Hb = (E + 255) / 256;
        gemm_hist_kernel<<<Nb + Hb, 256, 0, stream>>>(
            hidden, wpack_s, hsub, N, edges, deg, E, Nb);

        const int nb = (N + 2047) / 2048;            // <= 128 (bsum capacity)
        scan1_kernel<<<nb, 256, 0, stream>>>(deg, offs, bsum, N);
        scan3_kernel<<<(N + 255) / 256, 256, 0, stream>>>(
            offs, cursor, bsum, nodes, samp, N);
        scatter_kernel<<<(E + 255) / 256, 256, 0, stream>>>(
            edges, cursor, esorted, E);

        // Aggregation + final GEMM fused: writes hidden_new directly.
        node_agg_fused<<<(N + 15) / 16, 256, 0, stream>>>(
            esorted, hsub, relhr, qrW, walpha_w, walpha_b,
            deg, offs, wpack_h, hidnew, alpha_out, N);
    } else {
        // --- tier C fallback: push-style with atomics, fp32 GEMM ---
        hipMemsetAsync(hidnew, 0, (size_t)N * DIM * sizeof(float), stream);
        edge_kernel_fb<<<(E + 3) / 4, 256, 0, stream>>>(
            edges, hidden, rela, Ws, qrW, relhr, walpha_w, walpha_b,
            hidnew, alpha_out, E);
        gemm_n128<<<(N + 63) / 64, 256, 0, stream>>>(hidnew, Wh, hidnew, N);
        nodes_kernel<<<(N + 255) / 256, 256, 0, stream>>>(nodes, samp, N);
    }
}

// Round 14
// 202.704 us; speedup vs baseline: 1.2516x; 1.0380x over previous
//
#include <hip/hip_runtime.h>
#include <hip/hip_bf16.h>
#include <math.h>

// Problem constants (from reference): D = ATTN = 128, N_NODE = 100000.
#define DIM 128
#define N_NODE_C 100000

typedef __attribute__((ext_vector_type(8))) short  bf16x8;
typedef __attribute__((ext_vector_type(4))) float  f32x4;

__device__ inline unsigned short f2bf_rne(float f) {
    unsigned u = __float_as_uint(f);
    return (unsigned short)((u + 0x7FFFu + ((u >> 16) & 1u)) >> 16);
}
__device__ inline float bf2f(unsigned short u) {
    return __uint_as_float(((unsigned)u) << 16);
}

// ---------------------------------------------------------------------------
// Fused setup kernel (128 threads/block):
//   blocks [0, B)            : qrW[b]   = rela[q_rel[b]] @ Wqr_w + Wqr_b
//   blocks [B, B+RV)         : relhr[r] = [ rela[r] @ Wr | rela[r] ]  (256 c)
//   blocks [B+RV, B+RV+32)   : pack Ws / Wh into MFMA B-fragment layout
//   blocks [B+RV+32, ...)    : zero deg[] (replaces hipMemsetAsync)
// ---------------------------------------------------------------------------
__global__ __launch_bounds__(128) void setup_kernel(
    const int* __restrict__ q_rel,
    const float* __restrict__ rela,
    const float* __restrict__ Wqr_w,
    const float* __restrict__ Wqr_b,
    const float* __restrict__ Wr,
    const float* __restrict__ Ws,
    const float* __restrict__ Wh,
    float* __restrict__ qrW,
    float* __restrict__ relhr,
    uint4* __restrict__ wpack_s,
    uint4* __restrict__ wpack_h,
    int* deg, int N,
    int B, int RV)
{
    const int blk = blockIdx.x;
    const int j   = threadIdx.x;

    if (blk < B + RV) {
        __shared__ float emb[DIM];
        const float* W;
        float* out;
        float bias = 0.f;
        int row;
        if (blk < B) {
            row  = q_rel[blk];
            W    = Wqr_w;
            out  = qrW + (size_t)blk * DIM;
            bias = Wqr_b[j];
        } else {
            row = blk - B;
            W   = Wr;
            out = relhr + (size_t)(blk - B) * 256;
        }
        emb[j] = rela[(size_t)row * DIM + j];
        __syncthreads();

        float acc = bias;
#pragma unroll 8
        for (int k = 0; k < DIM; ++k)
            acc += emb[k] * W[k * DIM + j];
        out[j] = acc;
        if (blk >= B)
            out[128 + j] = emb[j];      // rela copy: free (already in LDS)
        return;
    }

    if (blk < B + RV + 32) {
        // --- pack path ---
        const int pid = blk - (B + RV);          // 0..31
        const float* W = (pid < 16) ? Ws : Wh;
        uint4* dst     = (pid < 16) ? wpack_s : wpack_h;
        const int id   = (pid & 15) * 128 + j;   // 0..2047
        const int ct   = id >> 8;
        const int kb   = (id >> 6) & 3;
        const int lane = id & 63;
        const int col  = ct * 16 + (lane & 15);
        const int k0   = kb * 32 + (lane >> 4) * 8;

        unsigned v[4];
#pragma unroll
        for (int p = 0; p < 4; ++p) {
            unsigned lo = f2bf_rne(W[(size_t)(k0 + 2 * p)     * DIM + col]);
            unsigned hi = f2bf_rne(W[(size_t)(k0 + 2 * p + 1) * DIM + col]);
            v[p] = lo | (hi << 16);
        }
        dst[id] = make_uint4(v[0], v[1], v[2], v[3]);
        return;
    }

    // --- deg zeroing path ---
    if (deg) {
        int i = (blk - (B + RV + 32)) * 128 + j;
        if (i < N) deg[i] = 0;
    }
}

// ---------------------------------------------------------------------------
// Fused GEMM + histogram. Heterogeneous grid:
//   blocks [0, Nb)      : hsub[M x 256] bf16 = [ bf16(A) | A @ W ]
//   blocks [Nb, Nb+Hb)  : deg histogram of edges obj column.
// C/D layout (HW-verified): col = lane&15, row = (lane>>4)*4 + reg.
// ---------------------------------------------------------------------------
__global__ __launch_bounds__(256) void gemm_hist_kernel(
    const float* __restrict__ A, const uint4* __restrict__ Wpack,
    unsigned short* __restrict__ H, int M,
    const int* __restrict__ edges, int* __restrict__ deg, int E, int Nb)
{
    if ((int)blockIdx.x >= Nb) {
        int i = ((int)blockIdx.x - Nb) * 256 + threadIdx.x;
        if (i < E) atomicAdd(&deg[edges[(size_t)i * 6 + 5]], 1);
        return;
    }

    __shared__ uint4 wlds[2048];   // [ct][kb][lane], 32 KB
    const int t = threadIdx.x;
#pragma unroll
    for (int p = 0; p < 8; ++p)
        wlds[p * 256 + t] = Wpack[p * 256 + t];
    __syncthreads();

    const int wave = t >> 6;
    const int lane = t & 63;
    const int r    = lane & 15;
    const int g    = lane >> 4;
    const int row0 = blockIdx.x * 64 + wave * 16;

    int arow = row0 + r;
    if (arow >= M) arow = M - 1;
    const float* Ap = A + (size_t)arow * DIM + g * 8;

    bf16x8 afrag[4];
#pragma unroll
    for (int kb = 0; kb < 4; ++kb) {
        const float4 lo = *(const float4*)(Ap + kb * 32);
        const float4 hi = *(const float4*)(Ap + kb * 32 + 4);
        bf16x8 a;
        a[0] = (short)f2bf_rne(lo.x); a[1] = (short)f2bf_rne(lo.y);
        a[2] = (short)f2bf_rne(lo.z); a[3] = (short)f2bf_rne(lo.w);
        a[4] = (short)f2bf_rne(hi.x); a[5] = (short)f2bf_rne(hi.y);
        a[6] = (short)f2bf_rne(hi.z); a[7] = (short)f2bf_rne(hi.w);
        afrag[kb] = a;
    }

    // bf16(A) into cols 0..127 (free conversion).
#pragma unroll
    for (int kb = 0; kb < 4; ++kb)
        *(bf16x8*)&H[(size_t)arow * 256 + kb * 32 + g * 8] = afrag[kb];

#pragma unroll
    for (int ct = 0; ct < 8; ++ct) {
        f32x4 acc = {0.f, 0.f, 0.f, 0.f};
#pragma unroll
        for (int kb = 0; kb < 4; ++kb) {
            bf16x8 b = *(bf16x8*)&wlds[ct * 256 + kb * 64 + lane];
            acc = __builtin_amdgcn_mfma_f32_16x16x32_bf16(afrag[kb], b, acc, 0, 0, 0);
        }
        const int col = ct * 16 + r;
#pragma unroll
        for (int jj = 0; jj < 4; ++jj) {
            const int row = row0 + g * 4 + jj;
            if (row < M)
                H[(size_t)row * 256 + 128 + col] = f2bf_rne(acc[jj]);
        }
    }
}

// ---------------------------------------------------------------------------
// Sort scaffolding.
// ---------------------------------------------------------------------------
__global__ __launch_bounds__(256) void scan1_kernel(
    const int* __restrict__ in, int* __restrict__ out,
    int* __restrict__ bsum, int n)
{
    __shared__ int ts[256];
    const int tid  = threadIdx.x;
    const int base = blockIdx.x * 2048 + tid * 8;

    int v[8];
    int run = 0;
#pragma unroll
    for (int i = 0; i < 8; ++i) {
        int x = (base + i < n) ? in[base + i] : 0;
        v[i] = run;
        run += x;
    }
    ts[tid] = run;
    __syncthreads();
    for (int off = 1; off < 256; off <<= 1) {
        int x = (tid >= off) ? ts[tid - off] : 0;
        __syncthreads();
        ts[tid] += x;
        __syncthreads();
    }
    const int excl = ts[tid] - run;
#pragma unroll
    for (int i = 0; i < 8; ++i)
        if (base + i < n) out[base + i] = v[i] + excl;
    if (tid == 255) bsum[blockIdx.x] = ts[255];
}

// Adds cross-block prefix (bsum holds block totals), duplicates into cursor,
// and emits sampled_nodes_idx.
__global__ __launch_bounds__(256) void scan3_kernel(
    int* __restrict__ offs, int* __restrict__ cursor,
    const int* __restrict__ bsum,
    const int* __restrict__ nodes, float* __restrict__ samp, int n)
{
    __shared__ int pref;
    if (threadIdx.x == 0) {
        int run = 0;
        const int lim = blockIdx.x >> 3;   // 8 scan3 blocks per scan1 block
        for (int i = 0; i < lim; ++i) run += bsum[i];
        pref = run;
    }
    __syncthreads();
    int i = blockIdx.x * 256 + threadIdx.x;
    if (i < n) {
        int v = offs[i] + pref;
        offs[i]   = v;
        cursor[i] = v;
        int nv = nodes[(size_t)i * 2 + 1];
        samp[i] = (nv > -1 && nv < N_NODE_C + 1) ? 1.f : 0.f;
    }
}

// Scatter full edge records {r_idx, rel, sub, e} in obj-sorted order.
__global__ __launch_bounds__(256) void scatter_kernel(
    const int* __restrict__ edges, int* __restrict__ cursor,
    int4* __restrict__ esorted, int E)
{
    int i = blockIdx.x * 256 + threadIdx.x;
    if (i < E) {
        int4 rec;
        rec.x = edges[(size_t)i * 6 + 0];
        rec.y = edges[(size_t)i * 6 + 2];
        rec.z = edges[(size_t)i * 6 + 4];
        rec.w = i;
        int obj = edges[(size_t)i * 6 + 5];
        int pos = atomicAdd(&cursor[obj], 1);
        esorted[pos] = rec;
    }
}

// ---------------------------------------------------------------------------
// Per-edge compute (shared).
// ---------------------------------------------------------------------------
__device__ inline void edge_compute(
    const int4 rec, const bf16x8 hb, const bf16x8 pb,
    const float* __restrict__ relhr, const float* __restrict__ qrW,
    const float4 wwA, const float4 wwB, const float wb,
    int j, int l16,
    float4& accA, float4& accB, float* __restrict__ alpha_out)
{
    const float* rr = &relhr[(size_t)rec.y * 256];
    const float4 bA  = *(const float4*)&rr[j];
    const float4 bB  = *(const float4*)&rr[j + 4];
    const float4 rvA = *(const float4*)&rr[128 + j];
    const float4 rvB = *(const float4*)&rr[128 + j + 4];
    const float4 cA  = *(const float4*)&qrW[(size_t)rec.x * DIM + j];
    const float4 cB  = *(const float4*)&qrW[(size_t)rec.x * DIM + j + 4];

    float sdot =
        fmaxf(bf2f((unsigned short)pb[0]) + bA.x + cA.x, 0.f) * wwA.x +
        fmaxf(bf2f((unsigned short)pb[1]) + bA.y + cA.y, 0.f) * wwA.y +
        fmaxf(bf2f((unsigned short)pb[2]) + bA.z + cA.z, 0.f) * wwA.z +
        fmaxf(bf2f((unsigned short)pb[3]) + bA.w + cA.w, 0.f) * wwA.w +
        fmaxf(bf2f((unsigned short)pb[4]) + bB.x + cB.x, 0.f) * wwB.x +
        fmaxf(bf2f((unsigned short)pb[5]) + bB.y + cB.y, 0.f) * wwB.y +
        fmaxf(bf2f((unsigned short)pb[6]) + bB.z + cB.z, 0.f) * wwB.z +
        fmaxf(bf2f((unsigned short)pb[7]) + bB.w + cB.w, 0.f) * wwB.w;

#pragma unroll
    for (int off = 8; off >= 1; off >>= 1)
        sdot += __shfl_xor(sdot, off, 16);

    const float alpha =
        __builtin_amdgcn_rcpf(1.f + __expf(-(sdot + wb)));

    accA.x += alpha * (bf2f((unsigned short)hb[0]) + rvA.x);
    accA.y += alpha * (bf2f((unsigned short)hb[1]) + rvA.y);
    accA.z += alpha * (bf2f((unsigned short)hb[2]) + rvA.z);
    accA.w += alpha * (bf2f((unsigned short)hb[3]) + rvA.w);
    accB.x += alpha * (bf2f((unsigned short)hb[4]) + rvB.x);
    accB.y += alpha * (bf2f((unsigned short)hb[5]) + rvB.y);
    accB.z += alpha * (bf2f((unsigned short)hb[6]) + rvB.z);
    accB.w += alpha * (bf2f((unsigned short)hb[7]) + rvB.w);

    if (l16 == 0) alpha_out[rec.w] = alpha;
}

// ---------------------------------------------------------------------------
// Fused pull-aggregation + final GEMM.
// Phase 1: one node per 16-lane group (16 nodes/block), serial edge walk with
//   1-deep record prefetch, acc in registers.
// Phase 2: acc rows -> LDS tile (bf16, padded), __syncthreads, then the
//   block's 4 waves compute tile[16x128] @ Wh[128x128] via MFMA, with B
//   fragments read DIRECTLY from global wpack_h (32 KB, L2-resident across
//   all 6250 blocks) — no LDS staging. LDS drops 37 KB -> 4.4 KB, lifting
//   the blocks/CU cap 4 -> ~8 so the latency-bound gather phase has twice
//   the resident waves.
// ---------------------------------------------------------------------------
__global__ __launch_bounds__(256) void node_agg_fused(
    const int4* __restrict__ esorted,
    const unsigned short* __restrict__ hsub,   // N x 256 bf16: [hidden | hsW]
    const float* __restrict__ relhr,           // RV x 256 f32: [hrW | rela]
    const float* __restrict__ qrW,             // B x 128 f32
    const float* __restrict__ walpha_w,
    const float* __restrict__ walpha_b,
    const int* __restrict__ deg,
    const int* __restrict__ offs,
    const uint4* __restrict__ wpack_h,
    float* __restrict__ outC,                  // N x 128 f32 (hidden_new)
    float* __restrict__ alpha_out,
    int N)
{
    __shared__ unsigned short tile[16][136];   // padded: +8 bf16 per row

    const int t   = threadIdx.x;
    const int g16 = t >> 4;                    // group 0..15 = local node
    const int l16 = t & 15;
    const int j   = l16 * 8;
    const int o   = blockIdx.x * 16 + g16;

    float4 accA = make_float4(0.f, 0.f, 0.f, 0.f);
    float4 accB = make_float4(0.f, 0.f, 0.f, 0.f);

    if (o < N) {
        const int d = deg[o];
        const int s = offs[o];
        if (d > 0) {
            const float4 wwA = *(const float4*)&walpha_w[j];
            const float4 wwB = *(const float4*)&walpha_w[j + 4];
            const float  wb  = walpha_b[0];

            int4 rec = esorted[s];
            for (int k = 0; k < d; ++k) {
                const int4 nrec = (k + 1 < d) ? esorted[s + k + 1] : rec;
                const bf16x8 hb = *(const bf16x8*)&hsub[(size_t)rec.z * 256 + j];
                const bf16x8 pb = *(const bf16x8*)&hsub[(size_t)rec.z * 256 + 128 + j];
                edge_compute(rec, hb, pb, relhr, qrW,
                             wwA, wwB, wb, j, l16, accA, accB, alpha_out);
                rec = nrec;
            }
        }
    }

    // Phase 1 -> LDS (bf16), exactly the rounding the standalone GEMM applied.
    {
        bf16x8 ob;
        ob[0] = (short)f2bf_rne(accA.x); ob[1] = (short)f2bf_rne(accA.y);
        ob[2] = (short)f2bf_rne(accA.z); ob[3] = (short)f2bf_rne(accA.w);
        ob[4] = (short)f2bf_rne(accB.x); ob[5] = (short)f2bf_rne(accB.y);
        ob[6] = (short)f2bf_rne(accB.z); ob[7] = (short)f2bf_rne(accB.w);
        *(bf16x8*)&tile[g16][j] = ob;
    }
    __syncthreads();

    // Phase 2: 16x128 tile @ Wh. All 4 waves share the A fragment; wave w
    // computes col-tiles ct = 2w, 2w+1. B fragments straight from L2.
    const int wave = t >> 6;
    const int lane = t & 63;
    const int r    = lane & 15;
    const int g    = lane >> 4;

    bf16x8 afrag[4];
#pragma unroll
    for (int kb = 0; kb < 4; ++kb)
        afrag[kb] = *(const bf16x8*)&tile[r][kb * 32 + g * 8];

#pragma unroll
    for (int cti = 0; cti < 2; ++cti) {
        const int ct = wave * 2 + cti;
        f32x4 acc = {0.f, 0.f, 0.f, 0.f};
#pragma unroll
        for (int kb = 0; kb < 4; ++kb) {
            bf16x8 b = *(const bf16x8*)&wpack_h[ct * 256 + kb * 64 + lane];
            acc = __builtin_amdgcn_mfma_f32_16x16x32_bf16(afrag[kb], b, acc, 0, 0, 0);
        }
        const int col = ct * 16 + r;
#pragma unroll
        for (int jj = 0; jj < 4; ++jj) {
            const int row = blockIdx.x * 16 + g * 4 + jj;
            if (row < N)
                outC[(size_t)row * DIM + col] = acc[jj];
        }
    }
}

// ---------------------------------------------------------------------------
// Tier-C fallback: push-style edge kernel (inline hs @ Ws), f32 atomics.
// ---------------------------------------------------------------------------
__global__ __launch_bounds__(256) void edge_kernel_fb(
    const int* __restrict__ edges,
    const float* __restrict__ hidden,
    const float* __restrict__ rela,
    const float* __restrict__ Ws,
    const float* __restrict__ qrW,
    const float* __restrict__ relhr,
    const float* __restrict__ walpha_w,
    const float* __restrict__ walpha_b,
    float* __restrict__ agg,
    float* __restrict__ alpha_out,
    int E)
{
    const int widx = threadIdx.x >> 6;
    const int lane = threadIdx.x & 63;
    const int e    = blockIdx.x * 4 + widx;
    const bool valid = (e < E);
    const int ec   = valid ? e : 0;

    const int r_idx = edges[(size_t)ec * 6 + 0];
    const int rel   = edges[(size_t)ec * 6 + 2];
    const int sub   = edges[(size_t)ec * 6 + 4];
    const int obj   = edges[(size_t)ec * 6 + 5];

    const int j = lane * 2;

    const float2 hv = *(const float2*)&hidden[(size_t)sub * DIM + j];
    const float2 rv = *(const float2*)&rela[(size_t)rel * DIM + j];

    __shared__ float hrow[4][DIM];
    *(float2*)&hrow[widx][j] = hv;
    __syncthreads();
    float p0 = 0.f, p1 = 0.f;
#pragma unroll 4
    for (int k = 0; k < DIM; ++k) {
        float hk  = hrow[widx][k];
        float2 w2 = *(const float2*)&Ws[k * DIM + j];
        p0 += hk * w2.x;
        p1 += hk * w2.y;
    }

    const float2 b2 = *(const float2*)&relhr[(size_t)rel * 256 + j];
    const float2 c2 = *(const float2*)&qrW[(size_t)r_idx * DIM + j];
    p0 = fmaxf(p0 + b2.x + c2.x, 0.f);
    p1 = fmaxf(p1 + b2.y + c2.y, 0.f);

    const float2 ww = *(const float2*)&walpha_w[j];
    float s = p0 * ww.x + p1 * ww.y;
#pragma unroll
    for (int off = 32; off >= 1; off >>= 1)
        s += __shfl_xor(s, off, 64);

    const float alpha = 1.f / (1.f + expf(-(s + walpha_b[0])));

    if (valid) {
        const float m0 = alpha * (hv.x + rv.x);
        const float m1 = alpha * (hv.y + rv.y);
        atomicAdd(&agg[(size_t)obj * DIM + j], m0);
        atomicAdd(&agg[(size_t)obj * DIM + j + 1], m1);
        if (lane == 0) alpha_out[e] = alpha;
    }
}

__global__ __launch_bounds__(256, 3) void gemm_n128(
    const float* A,
    const float* __restrict__ W,
    float* C,
    int M)
{
    __shared__ __align__(16) float Alds[64][DIM];
    __shared__ __align__(16) float Wlds[32][DIM];

    const int t    = threadIdx.x;
    const int row0 = blockIdx.x * 64;
    const int tx   = t & 31;
    const int ty   = t >> 5;

#pragma unroll
    for (int p = 0; p < 8; ++p) {
        int idx = p * 1024 + t * 4;
        int r   = idx >> 7;
        int c   = idx & 127;
        int gr  = row0 + r;
        if (gr >= M) gr = M - 1;
        *(float4*)&Alds[r][c] = *(const float4*)&A[(size_t)gr * DIM + c];
    }

    float acc[8][4] = {};

    for (int kk = 0; kk < 4; ++kk) {
        __syncthreads();
        {
            const float* Wg = W + (size_t)kk * 32 * DIM;
#pragma unroll
            for (int p = 0; p < 4; ++p) {
                int idx = p * 1024 + t * 4;
                *(float4*)&Wlds[idx >> 7][idx & 127] = *(const float4*)&Wg[idx];
            }
        }
        __syncthreads();

#pragma unroll 2
        for (int k4 = 0; k4 < 32; k4 += 4) {
            const float4 w0 = *(const float4*)&Wlds[k4 + 0][tx * 4];
            const float4 w1 = *(const float4*)&Wlds[k4 + 1][tx * 4];
            const float4 w2 = *(const float4*)&Wlds[k4 + 2][tx * 4];
            const float4 w3 = *(const float4*)&Wlds[k4 + 3][tx * 4];
#pragma unroll
            for (int i = 0; i < 8; ++i) {
                const float4 a = *(const float4*)&Alds[ty * 8 + i][kk * 32 + k4];
                acc[i][0] = fmaf(a.w, w3.x, fmaf(a.z, w2.x, fmaf(a.y, w1.x, fmaf(a.x, w0.x, acc[i][0]))));
                acc[i][1] = fmaf(a.w, w3.y, fmaf(a.z, w2.y, fmaf(a.y, w1.y, fmaf(a.x, w0.y, acc[i][1]))));
                acc[i][2] = fmaf(a.w, w3.z, fmaf(a.z, w2.z, fmaf(a.y, w1.z, fmaf(a.x, w0.z, acc[i][2]))));
                acc[i][3] = fmaf(a.w, w3.w, fmaf(a.z, w2.w, fmaf(a.y, w1.w, fmaf(a.x, w0.w, acc[i][3]))));
            }
        }
    }
    __syncthreads();

#pragma unroll
    for (int i = 0; i < 8; ++i) {
        int gr = row0 + ty * 8 + i;
        if (gr < M) {
            float4 v = make_float4(acc[i][0], acc[i][1], acc[i][2], acc[i][3]);
            *(float4*)&C[(size_t)gr * DIM + tx * 4] = v;
        }
    }
}

__global__ __launch_bounds__(256) void nodes_kernel(
    const int* __restrict__ nodes, float* __restrict__ out, int N)
{
    int i = blockIdx.x * 256 + threadIdx.x;
    if (i < N) {
        int v = nodes[(size_t)i * 2 + 1];
        out[i] = (v > -1 && v < N_NODE_C + 1) ? 1.f : 0.f;
    }
}

// ---------------------------------------------------------------------------
extern "C" void kernel_launch(void* const* d_in, const int* in_sizes, int n_in,
                              void* d_out, int out_size, void* d_ws, size_t ws_size,
                              hipStream_t stream)
{
    const int*   q_rel    = (const int*)d_in[1];
    const float* hidden   = (const float*)d_in[2];
    const int*   edges    = (const int*)d_in[3];
    const int*   nodes    = (const int*)d_in[4];
    const float* rela     = (const float*)d_in[5];
    const float* Ws       = (const float*)d_in[6];
    const float* Wr       = (const float*)d_in[7];
    const float* Wqr_w    = (const float*)d_in[8];
    const float* Wqr_b    = (const float*)d_in[9];
    const float* walpha_w = (const float*)d_in[10];
    const float* walpha_b = (const float*)d_in[11];
    const float* Wh       = (const float*)d_in[12];

    const int B  = in_sizes[1];
    const int N  = in_sizes[2] / DIM;
    const int E  = in_sizes[3] / 6;
    const int RV = in_sizes[5] / DIM;

    float* out       = (float*)d_out;
    float* hidnew    = out;                          // N*128 f32
    float* alpha_out = out + (size_t)N * DIM;        // E
    float* samp      = alpha_out + (size_t)E;        // N

    // Workspace layout (16-B alignment maintained in declaration order).
    char* p = (char*)d_ws;
    float* qrW   = (float*)p;     p += (size_t)B * DIM * sizeof(float);
    float* relhr = (float*)p;     p += (size_t)RV * 256 * sizeof(float);
    uint4* wpack_s = (uint4*)p;   p += 2048 * sizeof(uint4);
    uint4* wpack_h = (uint4*)p;   p += 2048 * sizeof(uint4);
    int4*  esorted = (int4*)p;    p += (size_t)E * sizeof(int4);
    unsigned short* hsub = (unsigned short*)p;
    p += (size_t)N * 256 * sizeof(unsigned short);
    const size_t pre_int_bytes = (size_t)(p - (char*)d_ws);
    const size_t need_A = pre_int_bytes + ((size_t)3 * N + 128) * sizeof(int);

    const bool tierA = (ws_size >= need_A);

    int* deg = nullptr;
    int* offs = nullptr;
    int* cursor = nullptr;
    int* bsum = nullptr;
    if (tierA) {
        char* q = (char*)d_ws + pre_int_bytes;
        deg    = (int*)q;
        offs   = deg + N;
        cursor = offs + N;
        bsum   = cursor + N;
    }

    const int ZB = tierA ? (N + 127) / 128 : 0;
    setup_kernel<<<B + RV + 32 + ZB, 128, 0, stream>>>(
        q_rel, rela, Wqr_w, Wqr_b, Wr, Ws, Wh,
        qrW, relhr, wpack_s, wpack_h, deg, N, B, RV);

    if (tierA) {
        const int Nb = (N + 63) / 64;
        const int Hb = (E + 255) / 256;
        gemm_hist_kernel<<<Nb + Hb, 256, 0, stream>>>(
            hidden, wpack_s, hsub, N, edges, deg, E, Nb);

        const int nb = (N + 2047) / 2048;            // <= 128 (bsum capacity)
        scan1_kernel<<<nb, 256, 0, stream>>>(deg, offs, bsum, N);
        scan3_kernel<<<(N + 255) / 256, 256, 0, stream>>>(
            offs, cursor, bsum, nodes, samp, N);
        scatter_kernel<<<(E + 255) / 256, 256, 0, stream>>>(
            edges, cursor, esorted, E);

        // Aggregation + final GEMM fused: writes hidden_new directly.
        node_agg_fused<<<(N + 15) / 16, 256, 0, stream>>>(
            esorted, hsub, relhr, qrW, walpha_w, walpha_b,
            deg, offs, wpack_h, hidnew, alpha_out, N);
    } else {
        // --- tier C fallback: push-style with atomics, fp32 GEMM ---
        hipMemsetAsync(hidnew, 0, (size_t)N * DIM * sizeof(float), stream);
        edge_kernel_fb<<<(E + 3) / 4, 256, 0, stream>>>(
            edges, hidden, rela, Ws, qrW, relhr, walpha_w, walpha_b,
            hidnew, alpha_out, E);
        gemm_n128<<<(N + 63) / 64, 256, 0, stream>>>(hidnew, Wh, hidnew, N);
        nodes_kernel<<<(N + 255) / 256, 256, 0, stream>>>(nodes, samp, N);
    }
}